// Round 2
// baseline (1715.884 us; speedup 1.0000x reference)
//
#include <hip/hip_runtime.h>
#include <hip/hip_bf16.h>
#include <math.h>

// Problem constants
#define NB 8          // batch
#define NN 1024       // NQ = NK
#define ND 512        // DQ = DK = DV
#define NH 8          // heads
#define NDS 64        // head dim
#define NM 64         // NH * NB
#define LOG_A (-6.93147180559945f)     // -log(1024)
#define SQRT_V 4.75682846001088f       // 512^0.25
#define INV_SQRT_V 0.210224103813429f
#define INV_EPS 10000.0f               // 1/EPS

#define QS_FLOATS  ((size_t)NM * NN * NDS)  // 4,194,304 (16 MB)
#define UV_FLOATS  ((size_t)NM * NN)        // 65,536

// ---------------------------------------------------------------------------
// K1: out[(h*8+b)*1024+n][d] = (X[r] . W[c] + bias[c]) * scale   (c = h*64+d)
// ---------------------------------------------------------------------------
__global__ __launch_bounds__(256) void k_linproj(
    const float* __restrict__ X, const float* __restrict__ W,
    const float* __restrict__ bias, float* __restrict__ out, float scale)
{
  __shared__ float Xs[64][65];
  __shared__ float Ws[64][65];
  const int t = threadIdx.x;
  const int r0 = blockIdx.x * 64;
  const int c0 = blockIdx.y * 64;
  const int ti = t >> 4, tj = t & 15;
  float acc[4][4] = {};
  for (int k0 = 0; k0 < ND; k0 += 64) {
#pragma unroll
    for (int s = 0; s < 16; ++s) {
      int idx = t + s * 256;
      int rr = idx >> 6, kk = idx & 63;
      Xs[rr][kk] = X[(size_t)(r0 + rr) * ND + k0 + kk];
      Ws[rr][kk] = W[(size_t)(c0 + rr) * ND + k0 + kk];
    }
    __syncthreads();
#pragma unroll
    for (int kk = 0; kk < 64; ++kk) {
      float a[4], b[4];
#pragma unroll
      for (int q = 0; q < 4; ++q) { a[q] = Xs[ti * 4 + q][kk]; b[q] = Ws[tj * 4 + q][kk]; }
#pragma unroll
      for (int ii = 0; ii < 4; ++ii)
#pragma unroll
        for (int jj = 0; jj < 4; ++jj)
          acc[ii][jj] = fmaf(a[ii], b[jj], acc[ii][jj]);
    }
    __syncthreads();
  }
  const int bb = r0 >> 10;     // batch index
  const int h  = c0 >> 6;      // head index (c-tile == one head)
  float4 bv = *(const float4*)&bias[c0 + tj * 4];
#pragma unroll
  for (int ii = 0; ii < 4; ++ii) {
    int r = r0 + ti * 4 + ii;
    int n = r & 1023;
    float4 o;
    o.x = (acc[ii][0] + bv.x) * scale;
    o.y = (acc[ii][1] + bv.y) * scale;
    o.z = (acc[ii][2] + bv.z) * scale;
    o.w = (acc[ii][3] + bv.w) * scale;
    *(float4*)&out[((size_t)((h * NB + bb) * NN + n)) * NDS + tj * 4] = o;
  }
}

// ---------------------------------------------------------------------------
// K2: row squared-norms: nrm[row] = sum_d X[row][d]^2   (wave per row)
// ---------------------------------------------------------------------------
__global__ __launch_bounds__(256) void k_sqnorm(
    const float* __restrict__ X, float* __restrict__ nrm)
{
  const int t = threadIdx.x;
  const int row = blockIdx.x * 4 + (t >> 6);
  const int lane = t & 63;
  float v = X[(size_t)row * NDS + lane];
  float s = v * v;
#pragma unroll
  for (int off = 32; off >= 1; off >>= 1) s += __shfl_xor(s, off);
  if (lane == 0) nrm[row] = s;
}

// ---------------------------------------------------------------------------
// K3: dual_out[m][a] = LOG_A - LSE_b( din[m][b] - ce(a,b) )
//     ce(a,b) = sqrt(max(|A_a|^2 + |B_b|^2 - 2 A_a.B_b, 0)) * INV_EPS
//     (u-pass: A=qs,B=ks,din=ve ; v-pass: A=ks,B=qs,din=ue)
// ---------------------------------------------------------------------------
__global__ __launch_bounds__(256) void k_lse(
    const float* __restrict__ Arows, const float* __restrict__ Brows,
    const float* __restrict__ Anrm, const float* __restrict__ Bnrm,
    const float* __restrict__ dual_in, float* __restrict__ dual_out, int first)
{
  __shared__ float xsT[64][68];   // A tile, d-major (transposed)
  __shared__ float ysT[64][68];   // B tile, d-major
  __shared__ float din_s[NN];
  __shared__ float y2_s[NN];
  const int t = threadIdx.x;
  const int a0 = blockIdx.x * 64;
  const int m  = blockIdx.y;
  const size_t base = (size_t)m << 16;   // m * 1024 * 64

  if (first) {
    *(float4*)&din_s[t * 4] = make_float4(0.f, 0.f, 0.f, 0.f);
  } else {
    *(float4*)&din_s[t * 4] = *(const float4*)&dual_in[(size_t)m * NN + t * 4];
  }
  *(float4*)&y2_s[t * 4] = *(const float4*)&Bnrm[(size_t)m * NN + t * 4];
#pragma unroll
  for (int s = 0; s < 16; ++s) {
    int idx = t + s * 256;
    int rr = idx >> 6, dd = idx & 63;
    xsT[dd][rr] = Arows[base + (size_t)(a0 + rr) * NDS + dd];
  }
  const int ti = t >> 4, tj = t & 15;
  float x2r[4];
#pragma unroll
  for (int q = 0; q < 4; ++q) x2r[q] = Anrm[(size_t)m * NN + a0 + ti * 4 + q];
  float M[4], S[4];
#pragma unroll
  for (int q = 0; q < 4; ++q) { M[q] = -3.0e38f; S[q] = 0.f; }

  for (int bt = 0; bt < 16; ++bt) {
    __syncthreads();   // protect ysT from previous iteration's readers
#pragma unroll
    for (int s = 0; s < 16; ++s) {
      int idx = t + s * 256;
      int rr = idx >> 6, dd = idx & 63;
      ysT[dd][rr] = Brows[base + (size_t)(bt * 64 + rr) * NDS + dd];
    }
    __syncthreads();
    float acc[4][4] = {};
#pragma unroll
    for (int d = 0; d < 64; ++d) {
      float4 av = *(const float4*)&xsT[d][ti * 4];
      float4 bv = *(const float4*)&ysT[d][tj * 4];
      const float* ap = (const float*)&av;
      const float* bp = (const float*)&bv;
#pragma unroll
      for (int ii = 0; ii < 4; ++ii)
#pragma unroll
        for (int jj = 0; jj < 4; ++jj)
          acc[ii][jj] = fmaf(ap[ii], bp[jj], acc[ii][jj]);
    }
#pragma unroll
    for (int jj = 0; jj < 4; ++jj) {
      int b = bt * 64 + tj * 4 + jj;
      float vb = din_s[b];
      float y2 = y2_s[b];
#pragma unroll
      for (int ii = 0; ii < 4; ++ii) {
        float d2 = x2r[ii] + y2 - 2.f * acc[ii][jj];
        float ce = sqrtf(fmaxf(d2, 0.f)) * INV_EPS;
        float x  = vb - ce;
        float nm = fmaxf(M[ii], x);
        S[ii] = S[ii] * __expf(M[ii] - nm) + __expf(x - nm);
        M[ii] = nm;
      }
    }
  }
  // reduce across the 16 tj lanes (within-wave; lanes t = ti*16+tj)
#pragma unroll
  for (int off = 1; off <= 8; off <<= 1) {
#pragma unroll
    for (int q = 0; q < 4; ++q) {
      float Mo = __shfl_xor(M[q], off);
      float So = __shfl_xor(S[q], off);
      float nm = fmaxf(M[q], Mo);
      S[q] = S[q] * __expf(M[q] - nm) + So * __expf(Mo - nm);
      M[q] = nm;
    }
  }
  if (tj == 0) {
#pragma unroll
    for (int q = 0; q < 4; ++q)
      dual_out[(size_t)m * NN + a0 + ti * 4 + q] = LOG_A - M[q] - __logf(S[q]);
  }
}

// ---------------------------------------------------------------------------
// K4: O[m][i][d] = SQRT_V*qs[m][i][d] + sum_j exp(ue_i+ve_j-ce_ij) * vs[m][j][d]
// ---------------------------------------------------------------------------
__global__ __launch_bounds__(256) void k_pv(
    const float* __restrict__ qs, const float* __restrict__ ks,
    const float* __restrict__ vs, const float* __restrict__ qn,
    const float* __restrict__ kn, const float* __restrict__ ue,
    const float* __restrict__ ve, float* __restrict__ O)
{
  __shared__ float xsT[64][68];   // q tile, d-major
  __shared__ float yb[64][68];    // k tile d-major, then reused as P tile [i][j]
  __shared__ float vss[64][68];   // v tile, row-major [j][d]
  __shared__ float ve_s[NN];
  __shared__ float y2_s[NN];
  __shared__ float ue_s[64];
  const int t = threadIdx.x;
  const int i0 = blockIdx.x * 64;
  const int m  = blockIdx.y;
  const size_t base = (size_t)m << 16;

  *(float4*)&ve_s[t * 4] = *(const float4*)&ve[(size_t)m * NN + t * 4];
  *(float4*)&y2_s[t * 4] = *(const float4*)&kn[(size_t)m * NN + t * 4];
  if (t < 64) ue_s[t] = ue[(size_t)m * NN + i0 + t];
#pragma unroll
  for (int s = 0; s < 16; ++s) {
    int idx = t + s * 256;
    int rr = idx >> 6, dd = idx & 63;
    xsT[dd][rr] = qs[base + (size_t)(i0 + rr) * NDS + dd];
  }
  const int ti = t >> 4, tj = t & 15;
  float x2r[4];
#pragma unroll
  for (int q = 0; q < 4; ++q) x2r[q] = qn[(size_t)m * NN + i0 + ti * 4 + q];
  float pacc[4][4] = {};

  for (int bt = 0; bt < 16; ++bt) {
    __syncthreads();   // protect yb/vss from previous GEMM readers
#pragma unroll
    for (int s = 0; s < 16; ++s) {
      int idx = t + s * 256;
      int rr = idx >> 6, dd = idx & 63;
      yb[dd][rr]  = ks[base + (size_t)(bt * 64 + rr) * NDS + dd];
      vss[rr][dd] = vs[base + (size_t)(bt * 64 + rr) * NDS + dd];
    }
    __syncthreads();
    float acc[4][4] = {};
#pragma unroll
    for (int d = 0; d < 64; ++d) {
      float4 av = *(const float4*)&xsT[d][ti * 4];
      float4 bv = *(const float4*)&yb[d][tj * 4];
      const float* ap = (const float*)&av;
      const float* bp = (const float*)&bv;
#pragma unroll
      for (int ii = 0; ii < 4; ++ii)
#pragma unroll
        for (int jj = 0; jj < 4; ++jj)
          acc[ii][jj] = fmaf(ap[ii], bp[jj], acc[ii][jj]);
    }
    // p_ij in registers
    float p[4][4];
#pragma unroll
    for (int jj = 0; jj < 4; ++jj) {
      int b = bt * 64 + tj * 4 + jj;
      float vej = ve_s[b];
      float y2  = y2_s[b];
#pragma unroll
      for (int ii = 0; ii < 4; ++ii) {
        float d2 = x2r[ii] + y2 - 2.f * acc[ii][jj];
        float ce = sqrtf(fmaxf(d2, 0.f)) * INV_EPS;
        p[ii][jj] = __expf(ue_s[ti * 4 + ii] + vej - ce);
      }
    }
    __syncthreads();   // done reading yb as k-tile
    // store P tile into yb as ps[i][j]
#pragma unroll
    for (int ii = 0; ii < 4; ++ii) {
      float4 pv = make_float4(p[ii][0], p[ii][1], p[ii][2], p[ii][3]);
      *(float4*)&yb[ti * 4 + ii][tj * 4] = pv;
    }
    __syncthreads();
    // pacc[i][d] += P[i][j] * V[j][d]
#pragma unroll
    for (int k = 0; k < 64; ++k) {
      float a[4];
#pragma unroll
      for (int q = 0; q < 4; ++q) a[q] = yb[ti * 4 + q][k];
      float4 bv = *(const float4*)&vss[k][tj * 4];
      const float* bp = (const float*)&bv;
#pragma unroll
      for (int ii = 0; ii < 4; ++ii)
#pragma unroll
        for (int jj = 0; jj < 4; ++jj)
          pacc[ii][jj] = fmaf(a[ii], bp[jj], pacc[ii][jj]);
    }
  }
  __syncthreads();
#pragma unroll
  for (int ii = 0; ii < 4; ++ii) {
    float4 o;
    o.x = SQRT_V * xsT[tj * 4 + 0][ti * 4 + ii] + pacc[ii][0];
    o.y = SQRT_V * xsT[tj * 4 + 1][ti * 4 + ii] + pacc[ii][1];
    o.z = SQRT_V * xsT[tj * 4 + 2][ti * 4 + ii] + pacc[ii][2];
    o.w = SQRT_V * xsT[tj * 4 + 3][ti * 4 + ii] + pacc[ii][3];
    *(float4*)&O[base + (size_t)(i0 + ti * 4 + ii) * NDS + tj * 4] = o;
  }
}

// ---------------------------------------------------------------------------
// K5: out[r][c] = Om[r][c] + relu(Om[r] . Wo[c] + bo[c]),
//     Om[b*1024+n][h*64+d] = O[(h*8+b)][n][d]
// ---------------------------------------------------------------------------
__global__ __launch_bounds__(256) void k_out(
    const float* __restrict__ O, const float* __restrict__ Wo,
    const float* __restrict__ bo, float* __restrict__ out)
{
  __shared__ float As[64][65];
  __shared__ float Ws[64][65];
  const int t = threadIdx.x;
  const int r0 = blockIdx.x * 64;
  const int c0 = blockIdx.y * 64;
  const int bb = r0 >> 10;
  const int n0 = r0 & 1023;
  const int ti = t >> 4, tj = t & 15;
  float acc[4][4] = {};
  for (int kt = 0; kt < 8; ++kt) {
    const int k0 = kt * 64;
    const size_t ob = ((size_t)(kt * NB + bb)) << 16;  // head kt of batch bb
#pragma unroll
    for (int s = 0; s < 16; ++s) {
      int idx = t + s * 256;
      int rr = idx >> 6, kk = idx & 63;
      As[rr][kk] = O[ob + (size_t)(n0 + rr) * NDS + kk];
      Ws[rr][kk] = Wo[(size_t)(c0 + rr) * ND + k0 + kk];
    }
    __syncthreads();
#pragma unroll
    for (int kk = 0; kk < 64; ++kk) {
      float a[4], b[4];
#pragma unroll
      for (int q = 0; q < 4; ++q) { a[q] = As[ti * 4 + q][kk]; b[q] = Ws[tj * 4 + q][kk]; }
#pragma unroll
      for (int ii = 0; ii < 4; ++ii)
#pragma unroll
        for (int jj = 0; jj < 4; ++jj)
          acc[ii][jj] = fmaf(a[ii], b[jj], acc[ii][jj]);
    }
    __syncthreads();
  }
  const int h = c0 >> 6;
  const size_t ob2 = ((size_t)(h * NB + bb)) << 16;
  float4 bv = *(const float4*)&bo[c0 + tj * 4];
#pragma unroll
  for (int ii = 0; ii < 4; ++ii) {
    int r = r0 + ti * 4 + ii;
    int n = n0 + ti * 4 + ii;
    float4 ov = *(const float4*)&O[ob2 + (size_t)n * NDS + tj * 4];
    float4 res;
    res.x = ov.x + fmaxf(acc[ii][0] + bv.x, 0.f);
    res.y = ov.y + fmaxf(acc[ii][1] + bv.y, 0.f);
    res.z = ov.z + fmaxf(acc[ii][2] + bv.z, 0.f);
    res.w = ov.w + fmaxf(acc[ii][3] + bv.w, 0.f);
    *(float4*)&out[(size_t)r * ND + c0 + tj * 4] = res;
  }
}

// ---------------------------------------------------------------------------
extern "C" void kernel_launch(void* const* d_in, const int* in_sizes, int n_in,
                              void* d_out, int out_size, void* d_ws, size_t ws_size,
                              hipStream_t stream) {
  const float* Q  = (const float*)d_in[0];
  const float* K  = (const float*)d_in[1];
  const float* Wq = (const float*)d_in[2];
  const float* bq = (const float*)d_in[3];
  const float* Wk = (const float*)d_in[4];
  const float* bk = (const float*)d_in[5];
  const float* Wv = (const float*)d_in[6];
  const float* bv = (const float*)d_in[7];
  const float* Wo = (const float*)d_in[8];
  const float* bo = (const float*)d_in[9];
  float* out = (float*)d_out;

  // workspace layout (floats): qs, ks, vs, O, ue, ve, qn, kn  (~68 MB)
  const size_t need_bytes = (4 * QS_FLOATS + 4 * UV_FLOATS) * sizeof(float);
  if (ws_size < need_bytes) return;  // insufficient scratch -> visible failure

  float* ws = (float*)d_ws;
  float* qs = ws;
  float* ks = qs + QS_FLOATS;
  float* vs = ks + QS_FLOATS;
  float* O  = vs + QS_FLOATS;
  float* ue = O + QS_FLOATS;
  float* ve = ue + UV_FLOATS;
  float* qn = ve + UV_FLOATS;
  float* kn = qn + UV_FLOATS;

  dim3 blk(256);
  k_linproj<<<dim3(128, 8), blk, 0, stream>>>(Q, Wq, bq, qs, INV_SQRT_V);
  k_linproj<<<dim3(128, 8), blk, 0, stream>>>(K, Wk, bk, ks, INV_SQRT_V);
  k_linproj<<<dim3(128, 8), blk, 0, stream>>>(K, Wv, bv, vs, 1.0f);
  k_sqnorm<<<dim3(16384), blk, 0, stream>>>(qs, qn);
  k_sqnorm<<<dim3(16384), blk, 0, stream>>>(ks, kn);
  for (int it = 0; it < 3; ++it) {
    k_lse<<<dim3(16, 64), blk, 0, stream>>>(qs, ks, qn, kn, ve, ue, it == 0 ? 1 : 0);
    k_lse<<<dim3(16, 64), blk, 0, stream>>>(ks, qs, kn, qn, ue, ve, 0);
  }
  k_pv<<<dim3(16, 64), blk, 0, stream>>>(qs, ks, vs, qn, kn, ue, ve, O);
  k_out<<<dim3(128, 8), blk, 0, stream>>>(O, Wo, bo, out);
}

// Round 4
// 752.409 us; speedup vs baseline: 2.2805x; 2.2805x over previous
//
#include <hip/hip_runtime.h>
#include <hip/hip_bf16.h>
#include <math.h>

// Problem constants
#define NB 8          // batch
#define NN 1024       // NQ = NK
#define ND 512        // DQ = DK = DV
#define NH 8          // heads
#define NDS 64        // head dim
#define NM 64         // NH * NB
#define LOG_A (-6.93147180559945f)     // -log(1024)
#define SQRT_V 4.75682846001088f       // 512^0.25
#define INV_SQRT_V 0.210224103813429f
#define INV_EPS 10000.0f               // 1/EPS

#define SPLIT_ELEMS ((size_t)NM * NN * NDS)   // 4,194,304 u16 (8 MB)
#define QS_FLOATS   ((size_t)NM * NN * NDS)
#define UV_FLOATS   ((size_t)NM * NN)

typedef unsigned short u16;
typedef unsigned int   u32;
typedef __attribute__((ext_vector_type(8))) short bf16x8;   // 8 bf16 = 4 VGPR
typedef __attribute__((ext_vector_type(4))) float f32x4;

#define MFMA16(a,b,c) __builtin_amdgcn_mfma_f32_16x16x32_bf16(a,b,c,0,0,0)

__device__ __forceinline__ u16 f2bf(float x) {      // RNE float->bf16
  u32 u = __float_as_uint(x);
  u = (u + 0x7fffu + ((u >> 16) & 1u)) >> 16;
  return (u16)u;
}
__device__ __forceinline__ float bf2f(u16 h) {
  return __uint_as_float(((u32)h) << 16);
}

// ---------------------------------------------------------------------------
// K1: projection. val = (X[r].W[c] + bias[c]) * scale, c = h*64+d.
// mode 0: write bf16 split (oh,ol) [m][n][d] + row norms (nrm).
// mode 1: write bf16 transposed oT [m][d][n].
// ---------------------------------------------------------------------------
__global__ __launch_bounds__(256) void k_linproj(
    const float* __restrict__ X, const float* __restrict__ W,
    const float* __restrict__ bias, u16* __restrict__ oh,
    u16* __restrict__ ol, u16* __restrict__ oT,
    float* __restrict__ nrm, float scale, int mode)
{
  __shared__ float Xs[64][65];
  __shared__ float Ws[64][65];
  const int t = threadIdx.x;
  const int r0 = blockIdx.x * 64;
  const int h  = blockIdx.y;          // head = c-tile
  const int c0 = h * 64;
  const int ti = t >> 4, tj = t & 15;
  float acc[4][4] = {};
  for (int k0 = 0; k0 < ND; k0 += 64) {
#pragma unroll
    for (int s = 0; s < 16; ++s) {
      int idx = t + s * 256;
      int rr = idx >> 6, kk = idx & 63;
      Xs[rr][kk] = X[(size_t)(r0 + rr) * ND + k0 + kk];
      Ws[rr][kk] = W[(size_t)(c0 + rr) * ND + k0 + kk];
    }
    __syncthreads();
#pragma unroll
    for (int kk = 0; kk < 64; ++kk) {
      float a[4], b[4];
#pragma unroll
      for (int q = 0; q < 4; ++q) { a[q] = Xs[ti * 4 + q][kk]; b[q] = Ws[tj * 4 + q][kk]; }
#pragma unroll
      for (int ii = 0; ii < 4; ++ii)
#pragma unroll
        for (int jj = 0; jj < 4; ++jj)
          acc[ii][jj] = fmaf(a[ii], b[jj], acc[ii][jj]);
    }
    __syncthreads();
  }
  const int bb = r0 >> 10;
  const int n0 = r0 & 1023;
  float4 bv4 = *(const float4*)&bias[c0 + tj * 4];
  const float* bvp = (const float*)&bv4;
  float vals[4][4];
#pragma unroll
  for (int ii = 0; ii < 4; ++ii)
#pragma unroll
    for (int jj = 0; jj < 4; ++jj)
      vals[ii][jj] = (acc[ii][jj] + bvp[jj]) * scale;

  const size_t mrow = (size_t)(h * NB + bb) * NN;
  if (mode == 0) {
    float ns[4];
#pragma unroll
    for (int ii = 0; ii < 4; ++ii) {
      int n = n0 + ti * 4 + ii;
      size_t idx = (mrow + n) * NDS + tj * 4;
      u16 h_[4], l_[4];
      float s = 0.f;
#pragma unroll
      for (int jj = 0; jj < 4; ++jj) {
        float v = vals[ii][jj];
        s = fmaf(v, v, s);
        u16 hh = f2bf(v);
        h_[jj] = hh;
        l_[jj] = f2bf(v - bf2f(hh));
      }
      ns[ii] = s;
      uint2 ph, pl;
      ph.x = (u32)h_[0] | ((u32)h_[1] << 16);
      ph.y = (u32)h_[2] | ((u32)h_[3] << 16);
      pl.x = (u32)l_[0] | ((u32)l_[1] << 16);
      pl.y = (u32)l_[2] | ((u32)l_[3] << 16);
      *(uint2*)&oh[idx] = ph;
      *(uint2*)&ol[idx] = pl;
    }
    // reduce row norms across the 16 tj lanes
#pragma unroll
    for (int off = 1; off <= 8; off <<= 1)
#pragma unroll
      for (int ii = 0; ii < 4; ++ii)
        ns[ii] += __shfl_xor(ns[ii], off);
    if (tj == 0) {
#pragma unroll
      for (int ii = 0; ii < 4; ++ii)
        nrm[mrow + n0 + ti * 4 + ii] = ns[ii];
    }
  } else {
#pragma unroll
    for (int jj = 0; jj < 4; ++jj) {
      int d = tj * 4 + jj;
      uint2 p;
      p.x = (u32)f2bf(vals[0][jj]) | ((u32)f2bf(vals[1][jj]) << 16);
      p.y = (u32)f2bf(vals[2][jj]) | ((u32)f2bf(vals[3][jj]) << 16);
      *(uint2*)&oT[((size_t)(h * NB + bb) * NDS + d) * NN + n0 + ti * 4] = p;
    }
  }
}

// ---------------------------------------------------------------------------
// K2: MFMA LSE pass.
// dout[m][a] = LOG_A - LSE_b( din[m][b] - ce(a,b) ),
// ce = sqrt(max(|x_a|^2+|y_b|^2-2 x_a.y_b,0))*INV_EPS, dot via 2-term bf16 split.
// 4 waves x 16-row strips; B k-tile staged in LDS (full 64x64 coverage:
// each of 256 threads stages 16 contiguous u16 = 2x bf16x8).
// ---------------------------------------------------------------------------
__global__ __launch_bounds__(256) void k_lse_mfma(
    const u16* __restrict__ Ah_, const u16* __restrict__ Al_,
    const u16* __restrict__ Bh_, const u16* __restrict__ Bl_,
    const float* __restrict__ Anrm, const float* __restrict__ Bnrm,
    const float* __restrict__ din, float* __restrict__ dout, int first)
{
  __shared__ __align__(16) float din_s[NN];
  __shared__ __align__(16) float y2_s[NN];
  __shared__ __align__(16) u16 Bhs[64][72];
  __shared__ __align__(16) u16 Bls[64][72];
  const int t = threadIdx.x;
  const int m = blockIdx.y;
  const int a0 = blockIdx.x * 64;
  if (first) { *(float4*)&din_s[t * 4] = make_float4(0.f, 0.f, 0.f, 0.f); }
  else       { *(float4*)&din_s[t * 4] = *(const float4*)&din[(size_t)m * NN + t * 4]; }
  *(float4*)&y2_s[t * 4] = *(const float4*)&Bnrm[(size_t)m * NN + t * 4];

  const int w = t >> 6, l = t & 63;
  const int c = l & 15, kg = l >> 4;
  const int arow = a0 + w * 16;
  const size_t mbase = (size_t)m * NN * NDS;

  const u16* pah = &Ah_[mbase + (size_t)(arow + c) * NDS + kg * 8];
  const u16* pal = &Al_[mbase + (size_t)(arow + c) * NDS + kg * 8];
  bf16x8 A0h = *(const bf16x8*)pah;
  bf16x8 A1h = *(const bf16x8*)(pah + 32);
  bf16x8 A0l = *(const bf16x8*)pal;
  bf16x8 A1l = *(const bf16x8*)(pal + 32);

  float x2r[4];
#pragma unroll
  for (int r = 0; r < 4; ++r) x2r[r] = Anrm[(size_t)m * NN + arow + kg * 4 + r];
  float M[4], S[4];
#pragma unroll
  for (int r = 0; r < 4; ++r) { M[r] = -3.0e38f; S[r] = 0.f; }

  const int srow = t >> 2;            // 0..63
  const int skoff = (t & 3) * 16;     // 0,16,32,48 (16 u16 per thread)
  for (int bt = 0; bt < 16; ++bt) {
    const int b0 = bt * 64;
    __syncthreads();
    {
      const u16* gh = &Bh_[mbase + (size_t)(b0 + srow) * NDS + skoff];
      const u16* gl = &Bl_[mbase + (size_t)(b0 + srow) * NDS + skoff];
      *(bf16x8*)&Bhs[srow][skoff]     = *(const bf16x8*)gh;
      *(bf16x8*)&Bhs[srow][skoff + 8] = *(const bf16x8*)(gh + 8);
      *(bf16x8*)&Bls[srow][skoff]     = *(const bf16x8*)gl;
      *(bf16x8*)&Bls[srow][skoff + 8] = *(const bf16x8*)(gl + 8);
    }
    __syncthreads();
#pragma unroll
    for (int cf = 0; cf < 4; ++cf) {
      const int bl = cf * 16 + c;
      bf16x8 B0h = *(const bf16x8*)&Bhs[bl][kg * 8];
      bf16x8 B1h = *(const bf16x8*)&Bhs[bl][kg * 8 + 32];
      bf16x8 B0l = *(const bf16x8*)&Bls[bl][kg * 8];
      bf16x8 B1l = *(const bf16x8*)&Bls[bl][kg * 8 + 32];
      f32x4 acc = {0.f, 0.f, 0.f, 0.f};
      acc = MFMA16(A0h, B0h, acc);
      acc = MFMA16(A0h, B0l, acc);
      acc = MFMA16(A0l, B0h, acc);
      acc = MFMA16(A1h, B1h, acc);
      acc = MFMA16(A1h, B1l, acc);
      acc = MFMA16(A1l, B1h, acc);
      const int col = b0 + bl;
      const float vb = din_s[col];
      const float y2 = y2_s[col];
#pragma unroll
      for (int r = 0; r < 4; ++r) {
        float d2 = fmaf(-2.f, acc[r], x2r[r] + y2);
        float sq = __fsqrt_rn(fmaxf(d2, 0.f));
        float x  = fmaf(-INV_EPS, sq, vb);
        float d  = x - M[r];
        float e  = __expf(-fabsf(d));
        float s_hi = fmaf(S[r], e, 1.f);   // x > M
        float s_lo = S[r] + e;             // x <= M
        bool gt = d > 0.f;
        S[r] = gt ? s_hi : s_lo;
        M[r] = gt ? x : M[r];
      }
    }
  }
  // combine across the 16 col-lanes
#pragma unroll
  for (int off = 1; off <= 8; off <<= 1) {
#pragma unroll
    for (int r = 0; r < 4; ++r) {
      float Mo = __shfl_xor(M[r], off);
      float So = __shfl_xor(S[r], off);
      float nm = fmaxf(M[r], Mo);
      S[r] = S[r] * __expf(M[r] - nm) + So * __expf(Mo - nm);
      M[r] = nm;
    }
  }
  if (c == 0) {
#pragma unroll
    for (int r = 0; r < 4; ++r)
      dout[(size_t)m * NN + arow + kg * 4 + r] = LOG_A - M[r] - __logf(S[r]);
  }
}

// ---------------------------------------------------------------------------
// K3: MFMA PV pass. O[m][i][d] = SQRT_V*q[i][d] + sum_j exp(ue_i+ve_j-ce_ij) v[j][d]
// ---------------------------------------------------------------------------
__global__ __launch_bounds__(256) void k_pv_mfma(
    const u16* __restrict__ qh, const u16* __restrict__ ql,
    const u16* __restrict__ kh, const u16* __restrict__ kl,
    const u16* __restrict__ vT, const float* __restrict__ qn,
    const float* __restrict__ kn, const float* __restrict__ ue,
    const float* __restrict__ ve, float* __restrict__ O)
{
  __shared__ __align__(16) float ve_s[NN];
  __shared__ __align__(16) float y2_s[NN];
  __shared__ __align__(16) u16 Bhs[64][72];
  __shared__ __align__(16) u16 Bls[64][72];
  __shared__ __align__(16) u16 Vs[64][72];
  __shared__ __align__(16) u16 pT[4][16][72];
  const int t = threadIdx.x;
  const int m = blockIdx.y;
  const int a0 = blockIdx.x * 64;
  *(float4*)&ve_s[t * 4] = *(const float4*)&ve[(size_t)m * NN + t * 4];
  *(float4*)&y2_s[t * 4] = *(const float4*)&kn[(size_t)m * NN + t * 4];

  const int w = t >> 6, l = t & 63;
  const int c = l & 15, kg = l >> 4;
  const int arow = a0 + w * 16;
  const size_t mbase = (size_t)m * NN * NDS;

  const u16* pah = &qh[mbase + (size_t)(arow + c) * NDS + kg * 8];
  const u16* pal = &ql[mbase + (size_t)(arow + c) * NDS + kg * 8];
  bf16x8 A0h = *(const bf16x8*)pah;
  bf16x8 A1h = *(const bf16x8*)(pah + 32);
  bf16x8 A0l = *(const bf16x8*)pal;
  bf16x8 A1l = *(const bf16x8*)(pal + 32);

  float x2r[4], uer[4];
#pragma unroll
  for (int r = 0; r < 4; ++r) {
    x2r[r] = qn[(size_t)m * NN + arow + kg * 4 + r];
    uer[r] = ue[(size_t)m * NN + arow + kg * 4 + r];
  }
  f32x4 pacc[4];
#pragma unroll
  for (int df = 0; df < 4; ++df) pacc[df] = (f32x4){0.f, 0.f, 0.f, 0.f};

  const int srow = t >> 2;            // 0..63
  const int skoff = (t & 3) * 16;     // 16 u16 per thread
  for (int bt = 0; bt < 16; ++bt) {
    const int b0 = bt * 64;
    __syncthreads();
    {
      const u16* gh = &kh[mbase + (size_t)(b0 + srow) * NDS + skoff];
      const u16* gl = &kl[mbase + (size_t)(b0 + srow) * NDS + skoff];
      const u16* gv = &vT[((size_t)m * NDS + srow) * NN + b0 + skoff];
      *(bf16x8*)&Bhs[srow][skoff]     = *(const bf16x8*)gh;
      *(bf16x8*)&Bhs[srow][skoff + 8] = *(const bf16x8*)(gh + 8);
      *(bf16x8*)&Bls[srow][skoff]     = *(const bf16x8*)gl;
      *(bf16x8*)&Bls[srow][skoff + 8] = *(const bf16x8*)(gl + 8);
      *(bf16x8*)&Vs[srow][skoff]      = *(const bf16x8*)gv;
      *(bf16x8*)&Vs[srow][skoff + 8]  = *(const bf16x8*)(gv + 8);
    }
    __syncthreads();
#pragma unroll
    for (int cf = 0; cf < 4; ++cf) {
      const int bl = cf * 16 + c;
      bf16x8 B0h = *(const bf16x8*)&Bhs[bl][kg * 8];
      bf16x8 B1h = *(const bf16x8*)&Bhs[bl][kg * 8 + 32];
      bf16x8 B0l = *(const bf16x8*)&Bls[bl][kg * 8];
      bf16x8 B1l = *(const bf16x8*)&Bls[bl][kg * 8 + 32];
      f32x4 acc = {0.f, 0.f, 0.f, 0.f};
      acc = MFMA16(A0h, B0h, acc);
      acc = MFMA16(A0h, B0l, acc);
      acc = MFMA16(A0l, B0h, acc);
      acc = MFMA16(A1h, B1h, acc);
      acc = MFMA16(A1h, B1l, acc);
      acc = MFMA16(A1l, B1h, acc);
      const int col = b0 + bl;
      const float vej = ve_s[col];
      const float y2  = y2_s[col];
#pragma unroll
      for (int r = 0; r < 4; ++r) {
        float d2 = fmaf(-2.f, acc[r], x2r[r] + y2);
        float sq = __fsqrt_rn(fmaxf(d2, 0.f));
        float p  = __expf(fmaf(-INV_EPS, sq, uer[r] + vej));
        pT[w][kg * 4 + r][cf * 16 + c] = f2bf(p);
      }
    }
    // PV: A = P strip (16 rows x 64 j), B = V^T tile
    bf16x8 Pa0 = *(const bf16x8*)&pT[w][c][kg * 8];
    bf16x8 Pa1 = *(const bf16x8*)&pT[w][c][kg * 8 + 32];
#pragma unroll
    for (int df = 0; df < 4; ++df) {
      bf16x8 Vb0 = *(const bf16x8*)&Vs[df * 16 + c][kg * 8];
      bf16x8 Vb1 = *(const bf16x8*)&Vs[df * 16 + c][kg * 8 + 32];
      pacc[df] = MFMA16(Pa0, Vb0, pacc[df]);
      pacc[df] = MFMA16(Pa1, Vb1, pacc[df]);
    }
  }
  // epilogue: O = SQRT_V * q + pacc
#pragma unroll
  for (int df = 0; df < 4; ++df) {
#pragma unroll
    for (int r = 0; r < 4; ++r) {
      int row = arow + kg * 4 + r;
      int d = df * 16 + c;
      size_t qi = mbase + (size_t)row * NDS + d;
      float qv = bf2f(qh[qi]) + bf2f(ql[qi]);
      O[qi] = fmaf(SQRT_V, qv, pacc[df][r]);
    }
  }
}

// ---------------------------------------------------------------------------
// K4: out[r][c] = Om[r][c] + relu(Om[r].Wo[c] + bo[c]),
//     Om[b*1024+n][h*64+d] = O[(h*8+b)][n][d]
// ---------------------------------------------------------------------------
__global__ __launch_bounds__(256) void k_out(
    const float* __restrict__ O, const float* __restrict__ Wo,
    const float* __restrict__ bo, float* __restrict__ out)
{
  __shared__ float As[64][65];
  __shared__ float Ws[64][65];
  const int t = threadIdx.x;
  const int r0 = blockIdx.x * 64;
  const int c0 = blockIdx.y * 64;
  const int bb = r0 >> 10;
  const int n0 = r0 & 1023;
  const int ti = t >> 4, tj = t & 15;
  float acc[4][4] = {};
  for (int kt = 0; kt < 8; ++kt) {
    const int k0 = kt * 64;
    const size_t ob = ((size_t)(kt * NB + bb)) << 16;
#pragma unroll
    for (int s = 0; s < 16; ++s) {
      int idx = t + s * 256;
      int rr = idx >> 6, kk = idx & 63;
      As[rr][kk] = O[ob + (size_t)(n0 + rr) * NDS + kk];
      Ws[rr][kk] = Wo[(size_t)(c0 + rr) * ND + k0 + kk];
    }
    __syncthreads();
#pragma unroll
    for (int kk = 0; kk < 64; ++kk) {
      float a[4], b[4];
#pragma unroll
      for (int q = 0; q < 4; ++q) { a[q] = As[ti * 4 + q][kk]; b[q] = Ws[tj * 4 + q][kk]; }
#pragma unroll
      for (int ii = 0; ii < 4; ++ii)
#pragma unroll
        for (int jj = 0; jj < 4; ++jj)
          acc[ii][jj] = fmaf(a[ii], b[jj], acc[ii][jj]);
    }
    __syncthreads();
  }
  const int h = c0 >> 6;
  const size_t ob2 = ((size_t)(h * NB + bb)) << 16;
  float4 bv = *(const float4*)&bo[c0 + tj * 4];
#pragma unroll
  for (int ii = 0; ii < 4; ++ii) {
    int r = r0 + ti * 4 + ii;
    int n = n0 + ti * 4 + ii;
    float4 ov = *(const float4*)&O[ob2 + (size_t)n * NDS + tj * 4];
    float4 res;
    res.x = ov.x + fmaxf(acc[ii][0] + bv.x, 0.f);
    res.y = ov.y + fmaxf(acc[ii][1] + bv.y, 0.f);
    res.z = ov.z + fmaxf(acc[ii][2] + bv.z, 0.f);
    res.w = ov.w + fmaxf(acc[ii][3] + bv.w, 0.f);
    *(float4*)&out[(size_t)r * ND + c0 + tj * 4] = res;
  }
}

// ---------------------------------------------------------------------------
extern "C" void kernel_launch(void* const* d_in, const int* in_sizes, int n_in,
                              void* d_out, int out_size, void* d_ws, size_t ws_size,
                              hipStream_t stream) {
  const float* Q  = (const float*)d_in[0];
  const float* K  = (const float*)d_in[1];
  const float* Wq = (const float*)d_in[2];
  const float* bq = (const float*)d_in[3];
  const float* Wk = (const float*)d_in[4];
  const float* bk = (const float*)d_in[5];
  const float* Wv = (const float*)d_in[6];
  const float* bv = (const float*)d_in[7];
  const float* Wo = (const float*)d_in[8];
  const float* bo = (const float*)d_in[9];
  float* out = (float*)d_out;

  // workspace: qh,ql,kh,kl,vT (bf16, 40MB) + O f32 (16MB) + ue,ve,qn,kn (1MB) = 57MB
  const size_t need_bytes =
      5 * SPLIT_ELEMS * sizeof(u16) + QS_FLOATS * sizeof(float) +
      4 * UV_FLOATS * sizeof(float);
  if (ws_size < need_bytes) return;

  u16* qh = (u16*)d_ws;
  u16* ql = qh + SPLIT_ELEMS;
  u16* kh = ql + SPLIT_ELEMS;
  u16* kl = kh + SPLIT_ELEMS;
  u16* vT = kl + SPLIT_ELEMS;
  float* O  = (float*)(vT + SPLIT_ELEMS);
  float* ue = O + QS_FLOATS;
  float* ve = ue + UV_FLOATS;
  float* qn = ve + UV_FLOATS;
  float* kn = qn + UV_FLOATS;

  dim3 blk(256);
  k_linproj<<<dim3(128, 8), blk, 0, stream>>>(Q, Wq, bq, qh, ql, nullptr, qn, INV_SQRT_V, 0);
  k_linproj<<<dim3(128, 8), blk, 0, stream>>>(K, Wk, bk, kh, kl, nullptr, kn, INV_SQRT_V, 0);
  k_linproj<<<dim3(128, 8), blk, 0, stream>>>(K, Wv, bv, nullptr, nullptr, vT, nullptr, 1.0f, 1);
  for (int it = 0; it < 3; ++it) {
    k_lse_mfma<<<dim3(16, 64), blk, 0, stream>>>(qh, ql, kh, kl, qn, kn, ve, ue, it == 0 ? 1 : 0);
    k_lse_mfma<<<dim3(16, 64), blk, 0, stream>>>(kh, kl, qh, ql, kn, qn, ue, ve, 0);
  }
  k_pv_mfma<<<dim3(16, 64), blk, 0, stream>>>(qh, ql, kh, kl, vT, qn, kn, ue, ve, O);
  k_out<<<dim3(128, 8), blk, 0, stream>>>(O, Wo, bo, out);
}

// Round 5
// 438.434 us; speedup vs baseline: 3.9137x; 1.7161x over previous
//
#include <hip/hip_runtime.h>
#include <hip/hip_bf16.h>
#include <math.h>

// Problem constants
#define NB 8          // batch
#define NN 1024       // NQ = NK
#define ND 512        // DQ = DK = DV
#define NH 8          // heads
#define NDS 64        // head dim
#define NM 64         // NH * NB
#define LOG_A (-6.93147180559945f)     // -log(1024)
#define SQRT_V 4.75682846001088f       // 512^0.25
#define INV_SQRT_V 0.210224103813429f
#define INV_EPS 10000.0f               // 1/EPS

#define SPLIT_ELEMS ((size_t)NM * NN * NDS)   // 4,194,304 u16 (8 MB)
#define W_ELEMS     ((size_t)ND * ND)         // 262,144
#define UV_FLOATS   ((size_t)NM * NN)

typedef unsigned short u16;
typedef unsigned int   u32;
typedef __attribute__((ext_vector_type(8))) short bf16x8;   // 8 bf16 = 4 VGPR
typedef __attribute__((ext_vector_type(4))) float f32x4;

#define MFMA16(a,b,c) __builtin_amdgcn_mfma_f32_16x16x32_bf16(a,b,c,0,0,0)

__device__ __forceinline__ u16 f2bf(float x) {      // RNE float->bf16
  u32 u = __float_as_uint(x);
  u = (u + 0x7fffu + ((u >> 16) & 1u)) >> 16;
  return (u16)u;
}
__device__ __forceinline__ float bf2f(u16 h) {
  return __uint_as_float(((u32)h) << 16);
}
__device__ __forceinline__ float fast_sqrt(float x) {   // v_sqrt_f32, ~1ulp
  float r;
  asm("v_sqrt_f32 %0, %1" : "=v"(r) : "v"(x));
  return r;
}

// ---------------------------------------------------------------------------
// K0: elementwise f32 -> bf16 hi/lo split. grid*256*4 == element count.
// ---------------------------------------------------------------------------
__global__ __launch_bounds__(256) void k_split(
    const float* __restrict__ X, u16* __restrict__ hi, u16* __restrict__ lo)
{
  const size_t i = ((size_t)blockIdx.x * 256 + threadIdx.x) * 4;
  float4 v = *(const float4*)&X[i];
  const float* vp = (const float*)&v;
  u16 h[4], l[4];
#pragma unroll
  for (int j = 0; j < 4; ++j) {
    h[j] = f2bf(vp[j]);
    l[j] = f2bf(vp[j] - bf2f(h[j]));
  }
  uint2 ph, pl;
  ph.x = (u32)h[0] | ((u32)h[1] << 16);
  ph.y = (u32)h[2] | ((u32)h[3] << 16);
  pl.x = (u32)l[0] | ((u32)l[1] << 16);
  pl.y = (u32)l[2] | ((u32)l[3] << 16);
  *(uint2*)&hi[i] = ph;
  *(uint2*)&lo[i] = pl;
}

// ---------------------------------------------------------------------------
// K1: MFMA projection. val = (X[r].W[c] + bias[c]) * scale, c = h*64+d.
// X,W given as bf16 hi/lo splits; 3-MFMA product (hh+hl+lh).
// mode 0: write bf16 split (oh,ol) [m][n][d] + row norms (from hi+lo).
// mode 1: write bf16 transposed oT [m][d][n].
// ---------------------------------------------------------------------------
__global__ __launch_bounds__(256) void k_proj_mfma(
    const u16* __restrict__ Xh, const u16* __restrict__ Xl,
    const u16* __restrict__ Wh, const u16* __restrict__ Wl,
    const float* __restrict__ bias, u16* __restrict__ oh,
    u16* __restrict__ ol, u16* __restrict__ oT,
    float* __restrict__ nrm, float scale, int mode)
{
  __shared__ __align__(16) u16 Xhs[64][72];
  __shared__ __align__(16) u16 Xls[64][72];
  __shared__ __align__(16) u16 Whs[64][72];
  __shared__ __align__(16) u16 Wls[64][72];
  const int t = threadIdx.x;
  const int r0 = blockIdx.x * 64;
  const int h  = blockIdx.y;
  const int c0 = h * 64;
  const int w = t >> 6, l = t & 63;
  const int c = l & 15, kg = l >> 4;
  const int srow = t >> 2;
  const int skoff = (t & 3) * 16;

  f32x4 acc[4];
#pragma unroll
  for (int cf = 0; cf < 4; ++cf) acc[cf] = (f32x4){0.f, 0.f, 0.f, 0.f};

  for (int kt = 0; kt < 8; ++kt) {
    const int k0 = kt * 64;
    __syncthreads();
    {
      const u16* gxh = &Xh[(size_t)(r0 + srow) * ND + k0 + skoff];
      const u16* gxl = &Xl[(size_t)(r0 + srow) * ND + k0 + skoff];
      const u16* gwh = &Wh[(size_t)(c0 + srow) * ND + k0 + skoff];
      const u16* gwl = &Wl[(size_t)(c0 + srow) * ND + k0 + skoff];
      *(bf16x8*)&Xhs[srow][skoff]     = *(const bf16x8*)gxh;
      *(bf16x8*)&Xhs[srow][skoff + 8] = *(const bf16x8*)(gxh + 8);
      *(bf16x8*)&Xls[srow][skoff]     = *(const bf16x8*)gxl;
      *(bf16x8*)&Xls[srow][skoff + 8] = *(const bf16x8*)(gxl + 8);
      *(bf16x8*)&Whs[srow][skoff]     = *(const bf16x8*)gwh;
      *(bf16x8*)&Whs[srow][skoff + 8] = *(const bf16x8*)(gwh + 8);
      *(bf16x8*)&Wls[srow][skoff]     = *(const bf16x8*)gwl;
      *(bf16x8*)&Wls[srow][skoff + 8] = *(const bf16x8*)(gwl + 8);
    }
    __syncthreads();
#pragma unroll
    for (int ks = 0; ks < 2; ++ks) {
      bf16x8 Ah = *(const bf16x8*)&Xhs[w * 16 + c][ks * 32 + kg * 8];
      bf16x8 Al = *(const bf16x8*)&Xls[w * 16 + c][ks * 32 + kg * 8];
#pragma unroll
      for (int cf = 0; cf < 4; ++cf) {
        bf16x8 Bh = *(const bf16x8*)&Whs[cf * 16 + c][ks * 32 + kg * 8];
        bf16x8 Bl = *(const bf16x8*)&Wls[cf * 16 + c][ks * 32 + kg * 8];
        acc[cf] = MFMA16(Ah, Bh, acc[cf]);
        acc[cf] = MFMA16(Ah, Bl, acc[cf]);
        acc[cf] = MFMA16(Al, Bh, acc[cf]);
      }
    }
  }

  const int bb = r0 >> 10;
  const int n0 = r0 & 1023;
  const size_t mrow = (size_t)(h * NB + bb) * NN;
  if (mode == 0) {
    float ns[4] = {0.f, 0.f, 0.f, 0.f};
#pragma unroll
    for (int cf = 0; cf < 4; ++cf) {
      const int col = c0 + cf * 16 + c;
      const float bv = bias[col];
#pragma unroll
      for (int r = 0; r < 4; ++r) {
        float v = (acc[cf][r] + bv) * scale;
        u16 hv = f2bf(v);
        float vh = bf2f(hv);
        u16 lv = f2bf(v - vh);
        float vr = vh + bf2f(lv);
        ns[r] = fmaf(vr, vr, ns[r]);
        int n = n0 + w * 16 + kg * 4 + r;
        size_t idx = (mrow + n) * NDS + cf * 16 + c;
        oh[idx] = hv;
        ol[idx] = lv;
      }
    }
#pragma unroll
    for (int off = 1; off <= 8; off <<= 1)
#pragma unroll
      for (int r = 0; r < 4; ++r) ns[r] += __shfl_xor(ns[r], off);
    if (c == 0) {
#pragma unroll
      for (int r = 0; r < 4; ++r)
        nrm[mrow + n0 + w * 16 + kg * 4 + r] = ns[r];
    }
  } else {
#pragma unroll
    for (int cf = 0; cf < 4; ++cf) {
      const int d = cf * 16 + c;
      const float bv = bias[c0 + d];
      u16 p0 = f2bf((acc[cf][0] + bv) * scale);
      u16 p1 = f2bf((acc[cf][1] + bv) * scale);
      u16 p2 = f2bf((acc[cf][2] + bv) * scale);
      u16 p3 = f2bf((acc[cf][3] + bv) * scale);
      uint2 p;
      p.x = (u32)p0 | ((u32)p1 << 16);
      p.y = (u32)p2 | ((u32)p3 << 16);
      *(uint2*)&oT[((size_t)(h * NB + bb) * NDS + d) * NN + n0 + w * 16 + kg * 4] = p;
    }
  }
}

// ---------------------------------------------------------------------------
// K2: MFMA LSE pass (unchanged structure; fast sqrt).
// ---------------------------------------------------------------------------
__global__ __launch_bounds__(256) void k_lse_mfma(
    const u16* __restrict__ Ah_, const u16* __restrict__ Al_,
    const u16* __restrict__ Bh_, const u16* __restrict__ Bl_,
    const float* __restrict__ Anrm, const float* __restrict__ Bnrm,
    const float* __restrict__ din, float* __restrict__ dout, int first)
{
  __shared__ __align__(16) float din_s[NN];
  __shared__ __align__(16) float y2_s[NN];
  __shared__ __align__(16) u16 Bhs[64][72];
  __shared__ __align__(16) u16 Bls[64][72];
  const int t = threadIdx.x;
  const int m = blockIdx.y;
  const int a0 = blockIdx.x * 64;
  if (first) { *(float4*)&din_s[t * 4] = make_float4(0.f, 0.f, 0.f, 0.f); }
  else       { *(float4*)&din_s[t * 4] = *(const float4*)&din[(size_t)m * NN + t * 4]; }
  *(float4*)&y2_s[t * 4] = *(const float4*)&Bnrm[(size_t)m * NN + t * 4];

  const int w = t >> 6, l = t & 63;
  const int c = l & 15, kg = l >> 4;
  const int arow = a0 + w * 16;
  const size_t mbase = (size_t)m * NN * NDS;

  const u16* pah = &Ah_[mbase + (size_t)(arow + c) * NDS + kg * 8];
  const u16* pal = &Al_[mbase + (size_t)(arow + c) * NDS + kg * 8];
  bf16x8 A0h = *(const bf16x8*)pah;
  bf16x8 A1h = *(const bf16x8*)(pah + 32);
  bf16x8 A0l = *(const bf16x8*)pal;
  bf16x8 A1l = *(const bf16x8*)(pal + 32);

  float x2r[4];
#pragma unroll
  for (int r = 0; r < 4; ++r) x2r[r] = Anrm[(size_t)m * NN + arow + kg * 4 + r];
  float M[4], S[4];
#pragma unroll
  for (int r = 0; r < 4; ++r) { M[r] = -3.0e38f; S[r] = 0.f; }

  const int srow = t >> 2;
  const int skoff = (t & 3) * 16;
  for (int bt = 0; bt < 16; ++bt) {
    const int b0 = bt * 64;
    __syncthreads();
    {
      const u16* gh = &Bh_[mbase + (size_t)(b0 + srow) * NDS + skoff];
      const u16* gl = &Bl_[mbase + (size_t)(b0 + srow) * NDS + skoff];
      *(bf16x8*)&Bhs[srow][skoff]     = *(const bf16x8*)gh;
      *(bf16x8*)&Bhs[srow][skoff + 8] = *(const bf16x8*)(gh + 8);
      *(bf16x8*)&Bls[srow][skoff]     = *(const bf16x8*)gl;
      *(bf16x8*)&Bls[srow][skoff + 8] = *(const bf16x8*)(gl + 8);
    }
    __syncthreads();
#pragma unroll
    for (int cf = 0; cf < 4; ++cf) {
      const int bl = cf * 16 + c;
      bf16x8 B0h = *(const bf16x8*)&Bhs[bl][kg * 8];
      bf16x8 B1h = *(const bf16x8*)&Bhs[bl][kg * 8 + 32];
      bf16x8 B0l = *(const bf16x8*)&Bls[bl][kg * 8];
      bf16x8 B1l = *(const bf16x8*)&Bls[bl][kg * 8 + 32];
      f32x4 acc = {0.f, 0.f, 0.f, 0.f};
      acc = MFMA16(A0h, B0h, acc);
      acc = MFMA16(A0h, B0l, acc);
      acc = MFMA16(A0l, B0h, acc);
      acc = MFMA16(A1h, B1h, acc);
      acc = MFMA16(A1h, B1l, acc);
      acc = MFMA16(A1l, B1h, acc);
      const int col = b0 + bl;
      const float vb = din_s[col];
      const float y2 = y2_s[col];
#pragma unroll
      for (int r = 0; r < 4; ++r) {
        float d2 = fmaf(-2.f, acc[r], x2r[r] + y2);
        float sq = fast_sqrt(fmaxf(d2, 0.f));
        float x  = fmaf(-INV_EPS, sq, vb);
        float d  = x - M[r];
        float e  = __expf(-fabsf(d));
        float s_hi = fmaf(S[r], e, 1.f);   // x > M
        float s_lo = S[r] + e;             // x <= M
        bool gt = d > 0.f;
        S[r] = gt ? s_hi : s_lo;
        M[r] = gt ? x : M[r];
      }
    }
  }
#pragma unroll
  for (int off = 1; off <= 8; off <<= 1) {
#pragma unroll
    for (int r = 0; r < 4; ++r) {
      float Mo = __shfl_xor(M[r], off);
      float So = __shfl_xor(S[r], off);
      float nm = fmaxf(M[r], Mo);
      S[r] = S[r] * __expf(M[r] - nm) + So * __expf(Mo - nm);
      M[r] = nm;
    }
  }
  if (c == 0) {
#pragma unroll
    for (int r = 0; r < 4; ++r)
      dout[(size_t)m * NN + arow + kg * 4 + r] = LOG_A - M[r] - __logf(S[r]);
  }
}

// ---------------------------------------------------------------------------
// K3: MFMA PV pass; O written as bf16 hi/lo pairs.
// ---------------------------------------------------------------------------
__global__ __launch_bounds__(256) void k_pv_mfma(
    const u16* __restrict__ qh, const u16* __restrict__ ql,
    const u16* __restrict__ kh, const u16* __restrict__ kl,
    const u16* __restrict__ vT, const float* __restrict__ qn,
    const float* __restrict__ kn, const float* __restrict__ ue,
    const float* __restrict__ ve, u16* __restrict__ Oh_, u16* __restrict__ Ol_)
{
  __shared__ __align__(16) float ve_s[NN];
  __shared__ __align__(16) float y2_s[NN];
  __shared__ __align__(16) u16 Bhs[64][72];
  __shared__ __align__(16) u16 Bls[64][72];
  __shared__ __align__(16) u16 Vs[64][72];
  __shared__ __align__(16) u16 pT[4][16][72];
  const int t = threadIdx.x;
  const int m = blockIdx.y;
  const int a0 = blockIdx.x * 64;
  *(float4*)&ve_s[t * 4] = *(const float4*)&ve[(size_t)m * NN + t * 4];
  *(float4*)&y2_s[t * 4] = *(const float4*)&kn[(size_t)m * NN + t * 4];

  const int w = t >> 6, l = t & 63;
  const int c = l & 15, kg = l >> 4;
  const int arow = a0 + w * 16;
  const size_t mbase = (size_t)m * NN * NDS;

  const u16* pah = &qh[mbase + (size_t)(arow + c) * NDS + kg * 8];
  const u16* pal = &ql[mbase + (size_t)(arow + c) * NDS + kg * 8];
  bf16x8 A0h = *(const bf16x8*)pah;
  bf16x8 A1h = *(const bf16x8*)(pah + 32);
  bf16x8 A0l = *(const bf16x8*)pal;
  bf16x8 A1l = *(const bf16x8*)(pal + 32);

  float x2r[4], uer[4];
#pragma unroll
  for (int r = 0; r < 4; ++r) {
    x2r[r] = qn[(size_t)m * NN + arow + kg * 4 + r];
    uer[r] = ue[(size_t)m * NN + arow + kg * 4 + r];
  }
  f32x4 pacc[4];
#pragma unroll
  for (int df = 0; df < 4; ++df) pacc[df] = (f32x4){0.f, 0.f, 0.f, 0.f};

  const int srow = t >> 2;
  const int skoff = (t & 3) * 16;
  for (int bt = 0; bt < 16; ++bt) {
    const int b0 = bt * 64;
    __syncthreads();
    {
      const u16* gh = &kh[mbase + (size_t)(b0 + srow) * NDS + skoff];
      const u16* gl = &kl[mbase + (size_t)(b0 + srow) * NDS + skoff];
      const u16* gv = &vT[((size_t)m * NDS + srow) * NN + b0 + skoff];
      *(bf16x8*)&Bhs[srow][skoff]     = *(const bf16x8*)gh;
      *(bf16x8*)&Bhs[srow][skoff + 8] = *(const bf16x8*)(gh + 8);
      *(bf16x8*)&Bls[srow][skoff]     = *(const bf16x8*)gl;
      *(bf16x8*)&Bls[srow][skoff + 8] = *(const bf16x8*)(gl + 8);
      *(bf16x8*)&Vs[srow][skoff]      = *(const bf16x8*)gv;
      *(bf16x8*)&Vs[srow][skoff + 8]  = *(const bf16x8*)(gv + 8);
    }
    __syncthreads();
#pragma unroll
    for (int cf = 0; cf < 4; ++cf) {
      const int bl = cf * 16 + c;
      bf16x8 B0h = *(const bf16x8*)&Bhs[bl][kg * 8];
      bf16x8 B1h = *(const bf16x8*)&Bhs[bl][kg * 8 + 32];
      bf16x8 B0l = *(const bf16x8*)&Bls[bl][kg * 8];
      bf16x8 B1l = *(const bf16x8*)&Bls[bl][kg * 8 + 32];
      f32x4 acc = {0.f, 0.f, 0.f, 0.f};
      acc = MFMA16(A0h, B0h, acc);
      acc = MFMA16(A0h, B0l, acc);
      acc = MFMA16(A0l, B0h, acc);
      acc = MFMA16(A1h, B1h, acc);
      acc = MFMA16(A1h, B1l, acc);
      acc = MFMA16(A1l, B1h, acc);
      const int col = b0 + bl;
      const float vej = ve_s[col];
      const float y2  = y2_s[col];
#pragma unroll
      for (int r = 0; r < 4; ++r) {
        float d2 = fmaf(-2.f, acc[r], x2r[r] + y2);
        float sq = fast_sqrt(fmaxf(d2, 0.f));
        float p  = __expf(fmaf(-INV_EPS, sq, uer[r] + vej));
        pT[w][kg * 4 + r][cf * 16 + c] = f2bf(p);
      }
    }
    bf16x8 Pa0 = *(const bf16x8*)&pT[w][c][kg * 8];
    bf16x8 Pa1 = *(const bf16x8*)&pT[w][c][kg * 8 + 32];
#pragma unroll
    for (int df = 0; df < 4; ++df) {
      bf16x8 Vb0 = *(const bf16x8*)&Vs[df * 16 + c][kg * 8];
      bf16x8 Vb1 = *(const bf16x8*)&Vs[df * 16 + c][kg * 8 + 32];
      pacc[df] = MFMA16(Pa0, Vb0, pacc[df]);
      pacc[df] = MFMA16(Pa1, Vb1, pacc[df]);
    }
  }
  // epilogue: O = SQRT_V * q + pacc, stored as bf16 hi/lo
#pragma unroll
  for (int df = 0; df < 4; ++df) {
#pragma unroll
    for (int r = 0; r < 4; ++r) {
      int row = arow + kg * 4 + r;
      int d = df * 16 + c;
      size_t qi = mbase + (size_t)row * NDS + d;
      float qv = bf2f(qh[qi]) + bf2f(ql[qi]);
      float o  = fmaf(SQRT_V, qv, pacc[df][r]);
      u16 hv = f2bf(o);
      Oh_[qi] = hv;
      Ol_[qi] = f2bf(o - bf2f(hv));
    }
  }
}

// ---------------------------------------------------------------------------
// K4: MFMA output GEMM. out[r][col] = Om[r][col] + relu(Om[r].Wo[col] + bo[col])
// Om stored as bf16 hi/lo in head-major layout [m][n][d].
// ---------------------------------------------------------------------------
__global__ __launch_bounds__(256) void k_out_mfma(
    const u16* __restrict__ Oh_, const u16* __restrict__ Ol_,
    const u16* __restrict__ Wh, const u16* __restrict__ Wl,
    const float* __restrict__ bo, float* __restrict__ out)
{
  __shared__ __align__(16) u16 Ahs[64][72];
  __shared__ __align__(16) u16 Als[64][72];
  __shared__ __align__(16) u16 Whs[64][72];
  __shared__ __align__(16) u16 Wls[64][72];
  const int t = threadIdx.x;
  const int r0 = blockIdx.x * 64;
  const int c0 = blockIdx.y * 64;
  const int bb = r0 >> 10;
  const int n0 = r0 & 1023;
  const int w = t >> 6, l = t & 63;
  const int c = l & 15, kg = l >> 4;
  const int srow = t >> 2;
  const int skoff = (t & 3) * 16;

  f32x4 acc[4];
#pragma unroll
  for (int cf = 0; cf < 4; ++cf) acc[cf] = (f32x4){0.f, 0.f, 0.f, 0.f};

  for (int kt = 0; kt < 8; ++kt) {
    __syncthreads();
    {
      const size_t ob = ((size_t)(kt * NB + bb) * NN + n0 + srow) * NDS;
      const u16* gah = &Oh_[ob + skoff];
      const u16* gal = &Ol_[ob + skoff];
      const u16* gwh = &Wh[(size_t)(c0 + srow) * ND + kt * 64 + skoff];
      const u16* gwl = &Wl[(size_t)(c0 + srow) * ND + kt * 64 + skoff];
      *(bf16x8*)&Ahs[srow][skoff]     = *(const bf16x8*)gah;
      *(bf16x8*)&Ahs[srow][skoff + 8] = *(const bf16x8*)(gah + 8);
      *(bf16x8*)&Als[srow][skoff]     = *(const bf16x8*)gal;
      *(bf16x8*)&Als[srow][skoff + 8] = *(const bf16x8*)(gal + 8);
      *(bf16x8*)&Whs[srow][skoff]     = *(const bf16x8*)gwh;
      *(bf16x8*)&Whs[srow][skoff + 8] = *(const bf16x8*)(gwh + 8);
      *(bf16x8*)&Wls[srow][skoff]     = *(const bf16x8*)gwl;
      *(bf16x8*)&Wls[srow][skoff + 8] = *(const bf16x8*)(gwl + 8);
    }
    __syncthreads();
#pragma unroll
    for (int ks = 0; ks < 2; ++ks) {
      bf16x8 Ah = *(const bf16x8*)&Ahs[w * 16 + c][ks * 32 + kg * 8];
      bf16x8 Al = *(const bf16x8*)&Als[w * 16 + c][ks * 32 + kg * 8];
#pragma unroll
      for (int cf = 0; cf < 4; ++cf) {
        bf16x8 Bh = *(const bf16x8*)&Whs[cf * 16 + c][ks * 32 + kg * 8];
        bf16x8 Bl = *(const bf16x8*)&Wls[cf * 16 + c][ks * 32 + kg * 8];
        acc[cf] = MFMA16(Ah, Bh, acc[cf]);
        acc[cf] = MFMA16(Ah, Bl, acc[cf]);
        acc[cf] = MFMA16(Al, Bh, acc[cf]);
      }
    }
  }
  // epilogue: + bias, relu, + residual Om
#pragma unroll
  for (int cf = 0; cf < 4; ++cf) {
    const int col = c0 + cf * 16 + c;
    const int d = cf * 16 + c;
    const float bv = bo[col];
#pragma unroll
    for (int r = 0; r < 4; ++r) {
      const int n = n0 + w * 16 + kg * 4 + r;
      const size_t oi = ((size_t)(blockIdx.y * NB + bb) * NN + n) * NDS + d;
      float om = bf2f(Oh_[oi]) + bf2f(Ol_[oi]);
      out[(size_t)(r0 + w * 16 + kg * 4 + r) * ND + col] =
          om + fmaxf(acc[cf][r] + bv, 0.f);
    }
  }
}

// ---------------------------------------------------------------------------
extern "C" void kernel_launch(void* const* d_in, const int* in_sizes, int n_in,
                              void* d_out, int out_size, void* d_ws, size_t ws_size,
                              hipStream_t stream) {
  const float* Q  = (const float*)d_in[0];
  const float* K  = (const float*)d_in[1];
  const float* Wq = (const float*)d_in[2];
  const float* bq = (const float*)d_in[3];
  const float* Wk = (const float*)d_in[4];
  const float* bk = (const float*)d_in[5];
  const float* Wv = (const float*)d_in[6];
  const float* bv = (const float*)d_in[7];
  const float* Wo = (const float*)d_in[8];
  const float* bo = (const float*)d_in[9];
  float* out = (float*)d_out;

  // ws layout (u16 unless noted):
  // qh ql kh kl vT Oh Ol (7 x SPLIT_ELEMS) | 8 W-splits (8 x W_ELEMS)
  // | ue ve qn kn (f32)
  const size_t need_bytes =
      7 * SPLIT_ELEMS * sizeof(u16) + 8 * W_ELEMS * sizeof(u16) +
      4 * UV_FLOATS * sizeof(float);
  if (ws_size < need_bytes) return;

  u16* qh = (u16*)d_ws;
  u16* ql = qh + SPLIT_ELEMS;
  u16* kh = ql + SPLIT_ELEMS;
  u16* kl = kh + SPLIT_ELEMS;
  u16* vT = kl + SPLIT_ELEMS;
  u16* Oh = vT + SPLIT_ELEMS;     // phase 1-2: raw Q split; phase 3+: O hi
  u16* Ol = Oh + SPLIT_ELEMS;     // phase 1-2: raw Q split lo; phase 3+: O lo
  u16* wqh = Ol + SPLIT_ELEMS;
  u16* wql = wqh + W_ELEMS;
  u16* wkh = wql + W_ELEMS;
  u16* wkl = wkh + W_ELEMS;
  u16* wvh = wkl + W_ELEMS;
  u16* wvl = wvh + W_ELEMS;
  u16* woh = wvl + W_ELEMS;
  u16* wol = woh + W_ELEMS;
  float* ue = (float*)(wol + W_ELEMS);
  float* ve = ue + UV_FLOATS;
  float* qn = ve + UV_FLOATS;
  float* kn = qn + UV_FLOATS;

  // raw input splits (aliased):
  u16* Qrh = Oh;                  // 8.4 MB
  u16* Qrl = Ol;
  u16* Krh = (u16*)d_out;         // d_out = 16.8 MB, fully overwritten at end
  u16* Krl = Krh + SPLIT_ELEMS;

  dim3 blk(256);
  // phase 0: splits
  k_split<<<dim3(4096), blk, 0, stream>>>(Q, Qrh, Qrl);
  k_split<<<dim3(4096), blk, 0, stream>>>(K, Krh, Krl);
  k_split<<<dim3(256), blk, 0, stream>>>(Wq, wqh, wql);
  k_split<<<dim3(256), blk, 0, stream>>>(Wk, wkh, wkl);
  k_split<<<dim3(256), blk, 0, stream>>>(Wv, wvh, wvl);
  k_split<<<dim3(256), blk, 0, stream>>>(Wo, woh, wol);
  // phase 1: projections (MFMA)
  k_proj_mfma<<<dim3(128, 8), blk, 0, stream>>>(Qrh, Qrl, wqh, wql, bq, qh, ql, nullptr, qn, INV_SQRT_V, 0);
  k_proj_mfma<<<dim3(128, 8), blk, 0, stream>>>(Krh, Krl, wkh, wkl, bk, kh, kl, nullptr, kn, INV_SQRT_V, 0);
  k_proj_mfma<<<dim3(128, 8), blk, 0, stream>>>(Krh, Krl, wvh, wvl, bv, nullptr, nullptr, vT, nullptr, 1.0f, 1);
  // phase 2: Sinkhorn
  for (int it = 0; it < 3; ++it) {
    k_lse_mfma<<<dim3(16, 64), blk, 0, stream>>>(qh, ql, kh, kl, qn, kn, ve, ue, it == 0 ? 1 : 0);
    k_lse_mfma<<<dim3(16, 64), blk, 0, stream>>>(kh, kl, qh, ql, kn, qn, ue, ve, 0);
  }
  // phase 3: PV (writes Oh/Ol over dead raw-Q split)
  k_pv_mfma<<<dim3(16, 64), blk, 0, stream>>>(qh, ql, kh, kl, vT, qn, kn, ue, ve, Oh, Ol);
  // phase 4: output GEMM (writes d_out over dead raw-K split)
  k_out_mfma<<<dim3(128, 8), blk, 0, stream>>>(Oh, Ol, woh, wol, bo, out);
}

// Round 6
// 397.430 us; speedup vs baseline: 4.3175x; 1.1032x over previous
//
#include <hip/hip_runtime.h>
#include <hip/hip_bf16.h>
#include <math.h>

// Problem constants
#define NB 8          // batch
#define NN 1024       // NQ = NK
#define ND 512        // DQ = DK = DV
#define NH 8          // heads
#define NDS 64        // head dim
#define NM 64         // NH * NB
#define LOG_A (-6.93147180559945f)     // -log(1024)
#define SQRT_V 4.75682846001088f       // 512^0.25
#define INV_SQRT_V 0.210224103813429f
#define INV_EPS 10000.0f               // 1/EPS
#define L2E  1.44269504088896f         // log2(e)
#define LN2F 0.693147180559945f
#define IEL2 14426.9504088896f         // INV_EPS * log2(e)

#define SPLIT_ELEMS ((size_t)NM * NN * NDS)   // 4,194,304 u16 (8 MB)
#define W_ELEMS     ((size_t)ND * ND)         // 262,144
#define UV_FLOATS   ((size_t)NM * NN)

typedef unsigned short u16;
typedef unsigned int   u32;
typedef __attribute__((ext_vector_type(8))) short bf16x8;   // 8 bf16 = 4 VGPR
typedef __attribute__((ext_vector_type(4))) float f32x4;

#define MFMA16(a,b,c) __builtin_amdgcn_mfma_f32_16x16x32_bf16(a,b,c,0,0,0)

__device__ __forceinline__ u16 f2bf(float x) {      // RNE float->bf16
  u32 u = __float_as_uint(x);
  u = (u + 0x7fffu + ((u >> 16) & 1u)) >> 16;
  return (u16)u;
}
__device__ __forceinline__ float bf2f(u16 h) {
  return __uint_as_float(((u32)h) << 16);
}
__device__ __forceinline__ float fast_sqrt(float x) {   // v_sqrt_f32
  float r;
  asm("v_sqrt_f32 %0, %1" : "=v"(r) : "v"(x));
  return r;
}
__device__ __forceinline__ float fast_exp2(float x) {   // v_exp_f32 = 2^x
  float r;
  asm("v_exp_f32 %0, %1" : "=v"(r) : "v"(x));
  return r;
}

// ---------------------------------------------------------------------------
// K0: elementwise f32 -> bf16 hi/lo split.
// ---------------------------------------------------------------------------
__global__ __launch_bounds__(256) void k_split(
    const float* __restrict__ X, u16* __restrict__ hi, u16* __restrict__ lo)
{
  const size_t i = ((size_t)blockIdx.x * 256 + threadIdx.x) * 4;
  float4 v = *(const float4*)&X[i];
  const float* vp = (const float*)&v;
  u16 h[4], l[4];
#pragma unroll
  for (int j = 0; j < 4; ++j) {
    h[j] = f2bf(vp[j]);
    l[j] = f2bf(vp[j] - bf2f(h[j]));
  }
  uint2 ph, pl;
  ph.x = (u32)h[0] | ((u32)h[1] << 16);
  ph.y = (u32)h[2] | ((u32)h[3] << 16);
  pl.x = (u32)l[0] | ((u32)l[1] << 16);
  pl.y = (u32)l[2] | ((u32)l[3] << 16);
  *(uint2*)&hi[i] = ph;
  *(uint2*)&lo[i] = pl;
}

// ---------------------------------------------------------------------------
// K1: MFMA projection (unchanged from round 5; passes).
// ---------------------------------------------------------------------------
__global__ __launch_bounds__(256) void k_proj_mfma(
    const u16* __restrict__ Xh, const u16* __restrict__ Xl,
    const u16* __restrict__ Wh, const u16* __restrict__ Wl,
    const float* __restrict__ bias, u16* __restrict__ oh,
    u16* __restrict__ ol, u16* __restrict__ oT,
    float* __restrict__ nrm, float scale, int mode)
{
  __shared__ __align__(16) u16 Xhs[64][72];
  __shared__ __align__(16) u16 Xls[64][72];
  __shared__ __align__(16) u16 Whs[64][72];
  __shared__ __align__(16) u16 Wls[64][72];
  const int t = threadIdx.x;
  const int r0 = blockIdx.x * 64;
  const int h  = blockIdx.y;
  const int c0 = h * 64;
  const int w = t >> 6, l = t & 63;
  const int c = l & 15, kg = l >> 4;
  const int srow = t >> 2;
  const int skoff = (t & 3) * 16;

  f32x4 acc[4];
#pragma unroll
  for (int cf = 0; cf < 4; ++cf) acc[cf] = (f32x4){0.f, 0.f, 0.f, 0.f};

  for (int kt = 0; kt < 8; ++kt) {
    const int k0 = kt * 64;
    __syncthreads();
    {
      const u16* gxh = &Xh[(size_t)(r0 + srow) * ND + k0 + skoff];
      const u16* gxl = &Xl[(size_t)(r0 + srow) * ND + k0 + skoff];
      const u16* gwh = &Wh[(size_t)(c0 + srow) * ND + k0 + skoff];
      const u16* gwl = &Wl[(size_t)(c0 + srow) * ND + k0 + skoff];
      *(bf16x8*)&Xhs[srow][skoff]     = *(const bf16x8*)gxh;
      *(bf16x8*)&Xhs[srow][skoff + 8] = *(const bf16x8*)(gxh + 8);
      *(bf16x8*)&Xls[srow][skoff]     = *(const bf16x8*)gxl;
      *(bf16x8*)&Xls[srow][skoff + 8] = *(const bf16x8*)(gxl + 8);
      *(bf16x8*)&Whs[srow][skoff]     = *(const bf16x8*)gwh;
      *(bf16x8*)&Whs[srow][skoff + 8] = *(const bf16x8*)(gwh + 8);
      *(bf16x8*)&Wls[srow][skoff]     = *(const bf16x8*)gwl;
      *(bf16x8*)&Wls[srow][skoff + 8] = *(const bf16x8*)(gwl + 8);
    }
    __syncthreads();
#pragma unroll
    for (int ks = 0; ks < 2; ++ks) {
      bf16x8 Ah = *(const bf16x8*)&Xhs[w * 16 + c][ks * 32 + kg * 8];
      bf16x8 Al = *(const bf16x8*)&Xls[w * 16 + c][ks * 32 + kg * 8];
#pragma unroll
      for (int cf = 0; cf < 4; ++cf) {
        bf16x8 Bh = *(const bf16x8*)&Whs[cf * 16 + c][ks * 32 + kg * 8];
        bf16x8 Bl = *(const bf16x8*)&Wls[cf * 16 + c][ks * 32 + kg * 8];
        acc[cf] = MFMA16(Ah, Bh, acc[cf]);
        acc[cf] = MFMA16(Ah, Bl, acc[cf]);
        acc[cf] = MFMA16(Al, Bh, acc[cf]);
      }
    }
  }

  const int bb = r0 >> 10;
  const int n0 = r0 & 1023;
  const size_t mrow = (size_t)(h * NB + bb) * NN;
  if (mode == 0) {
    float ns[4] = {0.f, 0.f, 0.f, 0.f};
#pragma unroll
    for (int cf = 0; cf < 4; ++cf) {
      const int col = c0 + cf * 16 + c;
      const float bv = bias[col];
#pragma unroll
      for (int r = 0; r < 4; ++r) {
        float v = (acc[cf][r] + bv) * scale;
        u16 hv = f2bf(v);
        float vh = bf2f(hv);
        u16 lv = f2bf(v - vh);
        float vr = vh + bf2f(lv);
        ns[r] = fmaf(vr, vr, ns[r]);
        int n = n0 + w * 16 + kg * 4 + r;
        size_t idx = (mrow + n) * NDS + cf * 16 + c;
        oh[idx] = hv;
        ol[idx] = lv;
      }
    }
#pragma unroll
    for (int off = 1; off <= 8; off <<= 1)
#pragma unroll
      for (int r = 0; r < 4; ++r) ns[r] += __shfl_xor(ns[r], off);
    if (c == 0) {
#pragma unroll
      for (int r = 0; r < 4; ++r)
        nrm[mrow + n0 + w * 16 + kg * 4 + r] = ns[r];
    }
  } else {
#pragma unroll
    for (int cf = 0; cf < 4; ++cf) {
      const int d = cf * 16 + c;
      const float bv = bias[c0 + d];
      u16 p0 = f2bf((acc[cf][0] + bv) * scale);
      u16 p1 = f2bf((acc[cf][1] + bv) * scale);
      u16 p2 = f2bf((acc[cf][2] + bv) * scale);
      u16 p3 = f2bf((acc[cf][3] + bv) * scale);
      uint2 p;
      p.x = (u32)p0 | ((u32)p1 << 16);
      p.y = (u32)p2 | ((u32)p3 << 16);
      *(uint2*)&oT[((size_t)(h * NB + bb) * NDS + d) * NN + n0 + w * 16 + kg * 4] = p;
    }
  }
}

// ---------------------------------------------------------------------------
// K2: MFMA LSE pass. log2-domain, deferred per-row flash update, XCD-grouped
// 1-D grid, async reg-staged K-tiles.
// ---------------------------------------------------------------------------
__global__ __launch_bounds__(256) void k_lse_mfma(
    const u16* __restrict__ Ah_, const u16* __restrict__ Al_,
    const u16* __restrict__ Bh_, const u16* __restrict__ Bl_,
    const float* __restrict__ Anrm, const float* __restrict__ Bnrm,
    const float* __restrict__ din, float* __restrict__ dout, int first)
{
  __shared__ __align__(16) float din_s[NN];   // pre-scaled by log2(e)
  __shared__ __align__(16) float y2_s[NN];
  __shared__ __align__(16) u16 Bhs[64][72];
  __shared__ __align__(16) u16 Bls[64][72];
  const int t = threadIdx.x;
  // XCD-grouping swizzle: all 16 a-blocks of head m share one XCD (id%8).
  const int Lb = blockIdx.x;
  const int xcd = Lb & 7, slot = Lb >> 3;
  const int m = xcd + 8 * (slot >> 4);
  const int a0 = (slot & 15) * 64;

  if (first) {
    *(float4*)&din_s[t * 4] = make_float4(0.f, 0.f, 0.f, 0.f);
  } else {
    float4 dv = *(const float4*)&din[(size_t)m * NN + t * 4];
    dv.x *= L2E; dv.y *= L2E; dv.z *= L2E; dv.w *= L2E;
    *(float4*)&din_s[t * 4] = dv;
  }
  *(float4*)&y2_s[t * 4] = *(const float4*)&Bnrm[(size_t)m * NN + t * 4];

  const int w = t >> 6, l = t & 63;
  const int c = l & 15, kg = l >> 4;
  const int arow = a0 + w * 16;
  const size_t mbase = (size_t)m * NN * NDS;

  const u16* pah = &Ah_[mbase + (size_t)(arow + c) * NDS + kg * 8];
  const u16* pal = &Al_[mbase + (size_t)(arow + c) * NDS + kg * 8];
  bf16x8 A0h = *(const bf16x8*)pah;
  bf16x8 A1h = *(const bf16x8*)(pah + 32);
  bf16x8 A0l = *(const bf16x8*)pal;
  bf16x8 A1l = *(const bf16x8*)(pal + 32);

  float x2r[4];
#pragma unroll
  for (int r = 0; r < 4; ++r) x2r[r] = Anrm[(size_t)m * NN + arow + kg * 4 + r];
  float M[4], S[4];
#pragma unroll
  for (int r = 0; r < 4; ++r) { M[r] = -3.0e38f; S[r] = 0.f; }

  const int srow = t >> 2;
  const int skoff = (t & 3) * 16;
  const u16* gh = &Bh_[mbase + (size_t)srow * NDS + skoff];
  const u16* gl = &Bl_[mbase + (size_t)srow * NDS + skoff];
  // prologue: tile 0 into regs
  bf16x8 rh0 = *(const bf16x8*)gh, rh1 = *(const bf16x8*)(gh + 8);
  bf16x8 rl0 = *(const bf16x8*)gl, rl1 = *(const bf16x8*)(gl + 8);

  for (int bt = 0; bt < 16; ++bt) {
    const int b0 = bt * 64;
    __syncthreads();                 // prev-tile readers done
    *(bf16x8*)&Bhs[srow][skoff]     = rh0;
    *(bf16x8*)&Bhs[srow][skoff + 8] = rh1;
    *(bf16x8*)&Bls[srow][skoff]     = rl0;
    *(bf16x8*)&Bls[srow][skoff + 8] = rl1;
    {   // prefetch next tile (wraps harmlessly at bt=15)
      const size_t noff = (size_t)((bt + 1) & 15) * 4096;
      rh0 = *(const bf16x8*)(gh + noff);
      rh1 = *(const bf16x8*)(gh + noff + 8);
      rl0 = *(const bf16x8*)(gl + noff);
      rl1 = *(const bf16x8*)(gl + noff + 8);
    }
    __syncthreads();                 // LDS writes visible
    f32x4 acc[4];
#pragma unroll
    for (int cf = 0; cf < 4; ++cf) {
      const int bl = cf * 16 + c;
      bf16x8 B0h = *(const bf16x8*)&Bhs[bl][kg * 8];
      bf16x8 B1h = *(const bf16x8*)&Bhs[bl][kg * 8 + 32];
      bf16x8 B0l = *(const bf16x8*)&Bls[bl][kg * 8];
      bf16x8 B1l = *(const bf16x8*)&Bls[bl][kg * 8 + 32];
      f32x4 a = {0.f, 0.f, 0.f, 0.f};
      a = MFMA16(A0h, B0h, a);
      a = MFMA16(A0h, B0l, a);
      a = MFMA16(A0l, B0h, a);
      a = MFMA16(A1h, B1h, a);
      a = MFMA16(A1h, B1l, a);
      a = MFMA16(A1l, B1h, a);
      acc[cf] = a;
    }
    float X[4][4];
#pragma unroll
    for (int cf = 0; cf < 4; ++cf) {
      const int col = b0 + cf * 16 + c;
      const float vb2 = din_s[col];
      const float y2  = y2_s[col];
#pragma unroll
      for (int r = 0; r < 4; ++r) {
        float d2 = fmaf(-2.f, acc[cf][r], x2r[r] + y2);
        float sq = fast_sqrt(fmaxf(d2, 0.f));
        X[cf][r] = fmaf(-IEL2, sq, vb2);
      }
    }
#pragma unroll
    for (int r = 0; r < 4; ++r) {
      float xm = fmaxf(fmaxf(X[0][r], X[1][r]), fmaxf(X[2][r], X[3][r]));
      float nm = fmaxf(M[r], xm);
      float s4 = fast_exp2(X[0][r] - nm) + fast_exp2(X[1][r] - nm)
               + fast_exp2(X[2][r] - nm) + fast_exp2(X[3][r] - nm);
      S[r] = fmaf(S[r], fast_exp2(M[r] - nm), s4);
      M[r] = nm;
    }
  }
  // combine across the 16 col-lanes
#pragma unroll
  for (int off = 1; off <= 8; off <<= 1) {
#pragma unroll
    for (int r = 0; r < 4; ++r) {
      float Mo = __shfl_xor(M[r], off);
      float So = __shfl_xor(S[r], off);
      float nm = fmaxf(M[r], Mo);
      S[r] = S[r] * fast_exp2(M[r] - nm) + So * fast_exp2(Mo - nm);
      M[r] = nm;
    }
  }
  if (c == 0) {
#pragma unroll
    for (int r = 0; r < 4; ++r)
      dout[(size_t)m * NN + arow + kg * 4 + r] =
          LOG_A - M[r] * LN2F - __logf(S[r]);
  }
}

// ---------------------------------------------------------------------------
// K3: MFMA PV pass. log2-domain, XCD-grouped, async reg-staged tiles.
// ---------------------------------------------------------------------------
__global__ __launch_bounds__(256) void k_pv_mfma(
    const u16* __restrict__ qh, const u16* __restrict__ ql,
    const u16* __restrict__ kh, const u16* __restrict__ kl,
    const u16* __restrict__ vT, const float* __restrict__ qn,
    const float* __restrict__ kn, const float* __restrict__ ue,
    const float* __restrict__ ve, u16* __restrict__ Oh_, u16* __restrict__ Ol_)
{
  __shared__ __align__(16) float ve_s[NN];   // pre-scaled by log2(e)
  __shared__ __align__(16) float y2_s[NN];
  __shared__ __align__(16) u16 Bhs[64][72];
  __shared__ __align__(16) u16 Bls[64][72];
  __shared__ __align__(16) u16 Vs[64][72];
  __shared__ __align__(16) u16 pT[4][16][72];
  const int t = threadIdx.x;
  const int Lb = blockIdx.x;
  const int xcd = Lb & 7, slot = Lb >> 3;
  const int m = xcd + 8 * (slot >> 4);
  const int a0 = (slot & 15) * 64;
  {
    float4 vv = *(const float4*)&ve[(size_t)m * NN + t * 4];
    vv.x *= L2E; vv.y *= L2E; vv.z *= L2E; vv.w *= L2E;
    *(float4*)&ve_s[t * 4] = vv;
  }
  *(float4*)&y2_s[t * 4] = *(const float4*)&kn[(size_t)m * NN + t * 4];

  const int w = t >> 6, l = t & 63;
  const int c = l & 15, kg = l >> 4;
  const int arow = a0 + w * 16;
  const size_t mbase = (size_t)m * NN * NDS;

  const u16* pah = &qh[mbase + (size_t)(arow + c) * NDS + kg * 8];
  const u16* pal = &ql[mbase + (size_t)(arow + c) * NDS + kg * 8];
  bf16x8 A0h = *(const bf16x8*)pah;
  bf16x8 A1h = *(const bf16x8*)(pah + 32);
  bf16x8 A0l = *(const bf16x8*)pal;
  bf16x8 A1l = *(const bf16x8*)(pal + 32);

  float x2r[4], uer2[4];
#pragma unroll
  for (int r = 0; r < 4; ++r) {
    x2r[r]  = qn[(size_t)m * NN + arow + kg * 4 + r];
    uer2[r] = ue[(size_t)m * NN + arow + kg * 4 + r] * L2E;
  }
  f32x4 pacc[4];
#pragma unroll
  for (int df = 0; df < 4; ++df) pacc[df] = (f32x4){0.f, 0.f, 0.f, 0.f};

  const int srow = t >> 2;
  const int skoff = (t & 3) * 16;
  const u16* gh = &kh[mbase + (size_t)srow * NDS + skoff];
  const u16* gl = &kl[mbase + (size_t)srow * NDS + skoff];
  const u16* gv = &vT[((size_t)m * NDS + srow) * NN + skoff];
  bf16x8 rh0 = *(const bf16x8*)gh, rh1 = *(const bf16x8*)(gh + 8);
  bf16x8 rl0 = *(const bf16x8*)gl, rl1 = *(const bf16x8*)(gl + 8);
  bf16x8 rv0 = *(const bf16x8*)gv, rv1 = *(const bf16x8*)(gv + 8);

  for (int bt = 0; bt < 16; ++bt) {
    const int b0 = bt * 64;
    __syncthreads();
    *(bf16x8*)&Bhs[srow][skoff]     = rh0;
    *(bf16x8*)&Bhs[srow][skoff + 8] = rh1;
    *(bf16x8*)&Bls[srow][skoff]     = rl0;
    *(bf16x8*)&Bls[srow][skoff + 8] = rl1;
    *(bf16x8*)&Vs[srow][skoff]      = rv0;
    *(bf16x8*)&Vs[srow][skoff + 8]  = rv1;
    {
      const int nbt = (bt + 1) & 15;
      const size_t nk = (size_t)nbt * 4096;   // K tiles: 64 rows * 64
      const size_t nv = (size_t)nbt * 64;     // V^T tiles: +64 columns
      rh0 = *(const bf16x8*)(gh + nk);
      rh1 = *(const bf16x8*)(gh + nk + 8);
      rl0 = *(const bf16x8*)(gl + nk);
      rl1 = *(const bf16x8*)(gl + nk + 8);
      rv0 = *(const bf16x8*)(gv + nv);
      rv1 = *(const bf16x8*)(gv + nv + 8);
    }
    __syncthreads();
    f32x4 acc[4];
#pragma unroll
    for (int cf = 0; cf < 4; ++cf) {
      const int bl = cf * 16 + c;
      bf16x8 B0h = *(const bf16x8*)&Bhs[bl][kg * 8];
      bf16x8 B1h = *(const bf16x8*)&Bhs[bl][kg * 8 + 32];
      bf16x8 B0l = *(const bf16x8*)&Bls[bl][kg * 8];
      bf16x8 B1l = *(const bf16x8*)&Bls[bl][kg * 8 + 32];
      f32x4 a = {0.f, 0.f, 0.f, 0.f};
      a = MFMA16(A0h, B0h, a);
      a = MFMA16(A0h, B0l, a);
      a = MFMA16(A0l, B0h, a);
      a = MFMA16(A1h, B1h, a);
      a = MFMA16(A1h, B1l, a);
      a = MFMA16(A1l, B1h, a);
      acc[cf] = a;
    }
#pragma unroll
    for (int cf = 0; cf < 4; ++cf) {
      const int col = b0 + cf * 16 + c;
      const float ve2 = ve_s[col];
      const float y2  = y2_s[col];
#pragma unroll
      for (int r = 0; r < 4; ++r) {
        float d2 = fmaf(-2.f, acc[cf][r], x2r[r] + y2);
        float sq = fast_sqrt(fmaxf(d2, 0.f));
        float p  = fast_exp2(fmaf(-IEL2, sq, uer2[r] + ve2));
        pT[w][kg * 4 + r][cf * 16 + c] = f2bf(p);
      }
    }
    bf16x8 Pa0 = *(const bf16x8*)&pT[w][c][kg * 8];
    bf16x8 Pa1 = *(const bf16x8*)&pT[w][c][kg * 8 + 32];
#pragma unroll
    for (int df = 0; df < 4; ++df) {
      bf16x8 Vb0 = *(const bf16x8*)&Vs[df * 16 + c][kg * 8];
      bf16x8 Vb1 = *(const bf16x8*)&Vs[df * 16 + c][kg * 8 + 32];
      pacc[df] = MFMA16(Pa0, Vb0, pacc[df]);
      pacc[df] = MFMA16(Pa1, Vb1, pacc[df]);
    }
  }
  // epilogue: O = SQRT_V * q + pacc, stored as bf16 hi/lo
#pragma unroll
  for (int df = 0; df < 4; ++df) {
#pragma unroll
    for (int r = 0; r < 4; ++r) {
      int row = arow + kg * 4 + r;
      int d = df * 16 + c;
      size_t qi = mbase + (size_t)row * NDS + d;
      float qv = bf2f(qh[qi]) + bf2f(ql[qi]);
      float o  = fmaf(SQRT_V, qv, pacc[df][r]);
      u16 hv = f2bf(o);
      Oh_[qi] = hv;
      Ol_[qi] = f2bf(o - bf2f(hv));
    }
  }
}

// ---------------------------------------------------------------------------
// K4: MFMA output GEMM (unchanged from round 5; passes).
// ---------------------------------------------------------------------------
__global__ __launch_bounds__(256) void k_out_mfma(
    const u16* __restrict__ Oh_, const u16* __restrict__ Ol_,
    const u16* __restrict__ Wh, const u16* __restrict__ Wl,
    const float* __restrict__ bo, float* __restrict__ out)
{
  __shared__ __align__(16) u16 Ahs[64][72];
  __shared__ __align__(16) u16 Als[64][72];
  __shared__ __align__(16) u16 Whs[64][72];
  __shared__ __align__(16) u16 Wls[64][72];
  const int t = threadIdx.x;
  const int r0 = blockIdx.x * 64;
  const int c0 = blockIdx.y * 64;
  const int bb = r0 >> 10;
  const int n0 = r0 & 1023;
  const int w = t >> 6, l = t & 63;
  const int c = l & 15, kg = l >> 4;
  const int srow = t >> 2;
  const int skoff = (t & 3) * 16;

  f32x4 acc[4];
#pragma unroll
  for (int cf = 0; cf < 4; ++cf) acc[cf] = (f32x4){0.f, 0.f, 0.f, 0.f};

  for (int kt = 0; kt < 8; ++kt) {
    __syncthreads();
    {
      const size_t ob = ((size_t)(kt * NB + bb) * NN + n0 + srow) * NDS;
      const u16* gah = &Oh_[ob + skoff];
      const u16* gal = &Ol_[ob + skoff];
      const u16* gwh = &Wh[(size_t)(c0 + srow) * ND + kt * 64 + skoff];
      const u16* gwl = &Wl[(size_t)(c0 + srow) * ND + kt * 64 + skoff];
      *(bf16x8*)&Ahs[srow][skoff]     = *(const bf16x8*)gah;
      *(bf16x8*)&Ahs[srow][skoff + 8] = *(const bf16x8*)(gah + 8);
      *(bf16x8*)&Als[srow][skoff]     = *(const bf16x8*)gal;
      *(bf16x8*)&Als[srow][skoff + 8] = *(const bf16x8*)(gal + 8);
      *(bf16x8*)&Whs[srow][skoff]     = *(const bf16x8*)gwh;
      *(bf16x8*)&Whs[srow][skoff + 8] = *(const bf16x8*)(gwh + 8);
      *(bf16x8*)&Wls[srow][skoff]     = *(const bf16x8*)gwl;
      *(bf16x8*)&Wls[srow][skoff + 8] = *(const bf16x8*)(gwl + 8);
    }
    __syncthreads();
#pragma unroll
    for (int ks = 0; ks < 2; ++ks) {
      bf16x8 Ah = *(const bf16x8*)&Ahs[w * 16 + c][ks * 32 + kg * 8];
      bf16x8 Al = *(const bf16x8*)&Als[w * 16 + c][ks * 32 + kg * 8];
#pragma unroll
      for (int cf = 0; cf < 4; ++cf) {
        bf16x8 Bh = *(const bf16x8*)&Whs[cf * 16 + c][ks * 32 + kg * 8];
        bf16x8 Bl = *(const bf16x8*)&Wls[cf * 16 + c][ks * 32 + kg * 8];
        acc[cf] = MFMA16(Ah, Bh, acc[cf]);
        acc[cf] = MFMA16(Ah, Bl, acc[cf]);
        acc[cf] = MFMA16(Al, Bh, acc[cf]);
      }
    }
  }
#pragma unroll
  for (int cf = 0; cf < 4; ++cf) {
    const int col = c0 + cf * 16 + c;
    const int d = cf * 16 + c;
    const float bv = bo[col];
#pragma unroll
    for (int r = 0; r < 4; ++r) {
      const int n = n0 + w * 16 + kg * 4 + r;
      const size_t oi = ((size_t)(blockIdx.y * NB + bb) * NN + n) * NDS + d;
      float om = bf2f(Oh_[oi]) + bf2f(Ol_[oi]);
      out[(size_t)(r0 + w * 16 + kg * 4 + r) * ND + col] =
          om + fmaxf(acc[cf][r] + bv, 0.f);
    }
  }
}

// ---------------------------------------------------------------------------
extern "C" void kernel_launch(void* const* d_in, const int* in_sizes, int n_in,
                              void* d_out, int out_size, void* d_ws, size_t ws_size,
                              hipStream_t stream) {
  const float* Q  = (const float*)d_in[0];
  const float* K  = (const float*)d_in[1];
  const float* Wq = (const float*)d_in[2];
  const float* bq = (const float*)d_in[3];
  const float* Wk = (const float*)d_in[4];
  const float* bk = (const float*)d_in[5];
  const float* Wv = (const float*)d_in[6];
  const float* bv = (const float*)d_in[7];
  const float* Wo = (const float*)d_in[8];
  const float* bo = (const float*)d_in[9];
  float* out = (float*)d_out;

  const size_t need_bytes =
      7 * SPLIT_ELEMS * sizeof(u16) + 8 * W_ELEMS * sizeof(u16) +
      4 * UV_FLOATS * sizeof(float);
  if (ws_size < need_bytes) return;

  u16* qh = (u16*)d_ws;
  u16* ql = qh + SPLIT_ELEMS;
  u16* kh = ql + SPLIT_ELEMS;
  u16* kl = kh + SPLIT_ELEMS;
  u16* vT = kl + SPLIT_ELEMS;
  u16* Oh = vT + SPLIT_ELEMS;     // phase 1-2: raw Q split; phase 3+: O hi
  u16* Ol = Oh + SPLIT_ELEMS;
  u16* wqh = Ol + SPLIT_ELEMS;
  u16* wql = wqh + W_ELEMS;
  u16* wkh = wql + W_ELEMS;
  u16* wkl = wkh + W_ELEMS;
  u16* wvh = wkl + W_ELEMS;
  u16* wvl = wvh + W_ELEMS;
  u16* woh = wvl + W_ELEMS;
  u16* wol = woh + W_ELEMS;
  float* ue = (float*)(wol + W_ELEMS);
  float* ve = ue + UV_FLOATS;
  float* qn = ve + UV_FLOATS;
  float* kn = qn + UV_FLOATS;

  u16* Qrh = Oh;                  // aliased raw input splits
  u16* Qrl = Ol;
  u16* Krh = (u16*)d_out;         // d_out fully overwritten at end
  u16* Krl = Krh + SPLIT_ELEMS;

  dim3 blk(256);
  k_split<<<dim3(4096), blk, 0, stream>>>(Q, Qrh, Qrl);
  k_split<<<dim3(4096), blk, 0, stream>>>(K, Krh, Krl);
  k_split<<<dim3(256), blk, 0, stream>>>(Wq, wqh, wql);
  k_split<<<dim3(256), blk, 0, stream>>>(Wk, wkh, wkl);
  k_split<<<dim3(256), blk, 0, stream>>>(Wv, wvh, wvl);
  k_split<<<dim3(256), blk, 0, stream>>>(Wo, woh, wol);
  k_proj_mfma<<<dim3(128, 8), blk, 0, stream>>>(Qrh, Qrl, wqh, wql, bq, qh, ql, nullptr, qn, INV_SQRT_V, 0);
  k_proj_mfma<<<dim3(128, 8), blk, 0, stream>>>(Krh, Krl, wkh, wkl, bk, kh, kl, nullptr, kn, INV_SQRT_V, 0);
  k_proj_mfma<<<dim3(128, 8), blk, 0, stream>>>(Krh, Krl, wvh, wvl, bv, nullptr, nullptr, vT, nullptr, 1.0f, 1);
  for (int it = 0; it < 3; ++it) {
    k_lse_mfma<<<dim3(1024), blk, 0, stream>>>(qh, ql, kh, kl, qn, kn, ve, ue, it == 0 ? 1 : 0);
    k_lse_mfma<<<dim3(1024), blk, 0, stream>>>(kh, kl, qh, ql, kn, qn, ue, ve, 0);
  }
  k_pv_mfma<<<dim3(1024), blk, 0, stream>>>(qh, ql, kh, kl, vT, qn, kn, ue, ve, Oh, Ol);
  k_out_mfma<<<dim3(128, 8), blk, 0, stream>>>(Oh, Ol, woh, wol, bo, out);
}

// Round 7
// 380.247 us; speedup vs baseline: 4.5125x; 1.0452x over previous
//
#include <hip/hip_runtime.h>
#include <hip/hip_bf16.h>
#include <math.h>

// Problem constants
#define NB 8          // batch
#define NN 1024       // NQ = NK
#define ND 512        // DQ = DK = DV
#define NH 8          // heads
#define NDS 64        // head dim
#define NM 64         // NH * NB
#define LOG_A (-6.93147180559945f)     // -log(1024)
#define SQRT_V 4.75682846001088f       // 512^0.25
#define INV_SQRT_V 0.210224103813429f
#define INV_EPS 10000.0f               // 1/EPS
#define L2E  1.44269504088896f         // log2(e)
#define LN2F 0.693147180559945f
#define IEL2 14426.9504088896f         // INV_EPS * log2(e)

#define SPLIT_ELEMS ((size_t)NM * NN * NDS)   // 4,194,304 u16 (8 MB)
#define W_ELEMS     ((size_t)ND * ND)         // 262,144
#define UV_FLOATS   ((size_t)NM * NN)

typedef unsigned short u16;
typedef unsigned int   u32;
typedef __attribute__((ext_vector_type(8))) short bf16x8;   // 8 bf16 = 4 VGPR
typedef __attribute__((ext_vector_type(4))) float f32x4;

#define MFMA16(a,b,c) __builtin_amdgcn_mfma_f32_16x16x32_bf16(a,b,c,0,0,0)

__device__ __forceinline__ u16 f2bf_t(float x) {    // truncating float->bf16
  return (u16)(__float_as_uint(x) >> 16);
}
__device__ __forceinline__ float bf2f(u16 h) {
  return __uint_as_float(((u32)h) << 16);
}
__device__ __forceinline__ float fast_sqrt(float x) {   // v_sqrt_f32
  float r;
  asm("v_sqrt_f32 %0, %1" : "=v"(r) : "v"(x));
  return r;
}
__device__ __forceinline__ float fast_exp2(float x) {   // v_exp_f32 = 2^x
  float r;
  asm("v_exp_f32 %0, %1" : "=v"(r) : "v"(x));
  return r;
}
__device__ __forceinline__ float max3f(float a, float b, float c) {
  float r;
  asm("v_max3_f32 %0, %1, %2, %3" : "=v"(r) : "v"(a), "v"(b), "v"(c));
  return r;
}

// ---------------------------------------------------------------------------
// K0: elementwise f32 -> bf16 hi/lo split (truncating).
// ---------------------------------------------------------------------------
__global__ __launch_bounds__(256) void k_split(
    const float* __restrict__ X, u16* __restrict__ hi, u16* __restrict__ lo)
{
  const size_t i = ((size_t)blockIdx.x * 256 + threadIdx.x) * 4;
  float4 v = *(const float4*)&X[i];
  const float* vp = (const float*)&v;
  u16 h[4], l[4];
#pragma unroll
  for (int j = 0; j < 4; ++j) {
    h[j] = f2bf_t(vp[j]);
    l[j] = f2bf_t(vp[j] - bf2f(h[j]));
  }
  uint2 ph, pl;
  ph.x = (u32)h[0] | ((u32)h[1] << 16);
  ph.y = (u32)h[2] | ((u32)h[3] << 16);
  pl.x = (u32)l[0] | ((u32)l[1] << 16);
  pl.y = (u32)l[2] | ((u32)l[3] << 16);
  *(uint2*)&hi[i] = ph;
  *(uint2*)&lo[i] = pl;
}

// ---------------------------------------------------------------------------
// K1: MFMA projection (round-5 structure; truncating epilogue).
// ---------------------------------------------------------------------------
__global__ __launch_bounds__(256) void k_proj_mfma(
    const u16* __restrict__ Xh, const u16* __restrict__ Xl,
    const u16* __restrict__ Wh, const u16* __restrict__ Wl,
    const float* __restrict__ bias, u16* __restrict__ oh,
    u16* __restrict__ ol, u16* __restrict__ oT,
    float* __restrict__ nrm, float scale, int mode)
{
  __shared__ __align__(16) u16 Xhs[64][72];
  __shared__ __align__(16) u16 Xls[64][72];
  __shared__ __align__(16) u16 Whs[64][72];
  __shared__ __align__(16) u16 Wls[64][72];
  const int t = threadIdx.x;
  const int r0 = blockIdx.x * 64;
  const int h  = blockIdx.y;
  const int c0 = h * 64;
  const int w = t >> 6, l = t & 63;
  const int c = l & 15, kg = l >> 4;
  const int srow = t >> 2;
  const int skoff = (t & 3) * 16;

  f32x4 acc[4];
#pragma unroll
  for (int cf = 0; cf < 4; ++cf) acc[cf] = (f32x4){0.f, 0.f, 0.f, 0.f};

  for (int kt = 0; kt < 8; ++kt) {
    const int k0 = kt * 64;
    __syncthreads();
    {
      const u16* gxh = &Xh[(size_t)(r0 + srow) * ND + k0 + skoff];
      const u16* gxl = &Xl[(size_t)(r0 + srow) * ND + k0 + skoff];
      const u16* gwh = &Wh[(size_t)(c0 + srow) * ND + k0 + skoff];
      const u16* gwl = &Wl[(size_t)(c0 + srow) * ND + k0 + skoff];
      *(bf16x8*)&Xhs[srow][skoff]     = *(const bf16x8*)gxh;
      *(bf16x8*)&Xhs[srow][skoff + 8] = *(const bf16x8*)(gxh + 8);
      *(bf16x8*)&Xls[srow][skoff]     = *(const bf16x8*)gxl;
      *(bf16x8*)&Xls[srow][skoff + 8] = *(const bf16x8*)(gxl + 8);
      *(bf16x8*)&Whs[srow][skoff]     = *(const bf16x8*)gwh;
      *(bf16x8*)&Whs[srow][skoff + 8] = *(const bf16x8*)(gwh + 8);
      *(bf16x8*)&Wls[srow][skoff]     = *(const bf16x8*)gwl;
      *(bf16x8*)&Wls[srow][skoff + 8] = *(const bf16x8*)(gwl + 8);
    }
    __syncthreads();
#pragma unroll
    for (int ks = 0; ks < 2; ++ks) {
      bf16x8 Ah = *(const bf16x8*)&Xhs[w * 16 + c][ks * 32 + kg * 8];
      bf16x8 Al = *(const bf16x8*)&Xls[w * 16 + c][ks * 32 + kg * 8];
#pragma unroll
      for (int cf = 0; cf < 4; ++cf) {
        bf16x8 Bh = *(const bf16x8*)&Whs[cf * 16 + c][ks * 32 + kg * 8];
        bf16x8 Bl = *(const bf16x8*)&Wls[cf * 16 + c][ks * 32 + kg * 8];
        acc[cf] = MFMA16(Ah, Bh, acc[cf]);
        acc[cf] = MFMA16(Ah, Bl, acc[cf]);
        acc[cf] = MFMA16(Al, Bh, acc[cf]);
      }
    }
  }

  const int bb = r0 >> 10;
  const int n0 = r0 & 1023;
  const size_t mrow = (size_t)(h * NB + bb) * NN;
  if (mode == 0) {
    float ns[4] = {0.f, 0.f, 0.f, 0.f};
#pragma unroll
    for (int cf = 0; cf < 4; ++cf) {
      const int col = c0 + cf * 16 + c;
      const float bv = bias[col];
#pragma unroll
      for (int r = 0; r < 4; ++r) {
        float v = (acc[cf][r] + bv) * scale;
        u16 hv = f2bf_t(v);
        u16 lv = f2bf_t(v - bf2f(hv));
        ns[r] = fmaf(v, v, ns[r]);
        int n = n0 + w * 16 + kg * 4 + r;
        size_t idx = (mrow + n) * NDS + cf * 16 + c;
        oh[idx] = hv;
        ol[idx] = lv;
      }
    }
#pragma unroll
    for (int off = 1; off <= 8; off <<= 1)
#pragma unroll
      for (int r = 0; r < 4; ++r) ns[r] += __shfl_xor(ns[r], off);
    if (c == 0) {
#pragma unroll
      for (int r = 0; r < 4; ++r)
        nrm[mrow + n0 + w * 16 + kg * 4 + r] = ns[r];
    }
  } else {
#pragma unroll
    for (int cf = 0; cf < 4; ++cf) {
      const int d = cf * 16 + c;
      const float bv = bias[c0 + d];
      u16 p0 = f2bf_t((acc[cf][0] + bv) * scale);
      u16 p1 = f2bf_t((acc[cf][1] + bv) * scale);
      u16 p2 = f2bf_t((acc[cf][2] + bv) * scale);
      u16 p3 = f2bf_t((acc[cf][3] + bv) * scale);
      uint2 p;
      p.x = (u32)p0 | ((u32)p1 << 16);
      p.y = (u32)p2 | ((u32)p3 << 16);
      *(uint2*)&oT[((size_t)(h * NB + bb) * NDS + d) * NN + n0 + w * 16 + kg * 4] = p;
    }
  }
}

// ---------------------------------------------------------------------------
// K2: MFMA LSE pass. 512 threads / 8 waves share staged B-tiles (halved
// staging per wave); log2-domain flash; max3; XCD-grouped.
// ---------------------------------------------------------------------------
__global__ __launch_bounds__(512, 6) void k_lse_mfma(
    const u16* __restrict__ Ah_, const u16* __restrict__ Al_,
    const u16* __restrict__ Bh_, const u16* __restrict__ Bl_,
    const float* __restrict__ Anrm, const float* __restrict__ Bnrm,
    const float* __restrict__ din, float* __restrict__ dout, int first)
{
  __shared__ __align__(16) float din_s[NN];   // pre-scaled by log2(e)
  __shared__ __align__(16) float y2_s[NN];
  __shared__ __align__(16) u16 Bhs[64][72];
  __shared__ __align__(16) u16 Bls[64][72];
  const int t = threadIdx.x;
  const int Lb = blockIdx.x;                  // 512 blocks
  const int xcd = Lb & 7, slot = Lb >> 3;     // slot 0..63
  const int m = xcd + 8 * (slot >> 3);
  const int a0 = (slot & 7) * 128;

  if (first) {
    *(float2*)&din_s[t * 2] = make_float2(0.f, 0.f);
  } else {
    float2 dv = *(const float2*)&din[(size_t)m * NN + t * 2];
    dv.x *= L2E; dv.y *= L2E;
    *(float2*)&din_s[t * 2] = dv;
  }
  *(float2*)&y2_s[t * 2] = *(const float2*)&Bnrm[(size_t)m * NN + t * 2];

  const int w = t >> 6, l = t & 63;
  const int c = l & 15, kg = l >> 4;
  const int arow = a0 + w * 16;
  const size_t mbase = (size_t)m * NN * NDS;

  const u16* pah = &Ah_[mbase + (size_t)(arow + c) * NDS + kg * 8];
  const u16* pal = &Al_[mbase + (size_t)(arow + c) * NDS + kg * 8];
  bf16x8 A0h = *(const bf16x8*)pah;
  bf16x8 A1h = *(const bf16x8*)(pah + 32);
  bf16x8 A0l = *(const bf16x8*)pal;
  bf16x8 A1l = *(const bf16x8*)(pal + 32);

  float x2r[4];
#pragma unroll
  for (int r = 0; r < 4; ++r) x2r[r] = Anrm[(size_t)m * NN + arow + kg * 4 + r];
  float M[4], S[4];
#pragma unroll
  for (int r = 0; r < 4; ++r) { M[r] = -3.0e38f; S[r] = 0.f; }

  const int srow = t >> 3;            // 0..63
  const int skoff = (t & 7) * 8;      // 8 u16 per thread per buffer
  const u16* gh = &Bh_[mbase + (size_t)srow * NDS + skoff];
  const u16* gl = &Bl_[mbase + (size_t)srow * NDS + skoff];
  bf16x8 rh = *(const bf16x8*)gh;
  bf16x8 rl = *(const bf16x8*)gl;

  for (int bt = 0; bt < 16; ++bt) {
    const int b0 = bt * 64;
    __syncthreads();                 // prev-tile readers done
    *(bf16x8*)&Bhs[srow][skoff] = rh;
    *(bf16x8*)&Bls[srow][skoff] = rl;
    {   // prefetch next tile (wraps harmlessly at bt=15)
      const size_t noff = (size_t)((bt + 1) & 15) * 4096;
      rh = *(const bf16x8*)(gh + noff);
      rl = *(const bf16x8*)(gl + noff);
    }
    __syncthreads();                 // LDS writes visible
    f32x4 acc[4];
#pragma unroll
    for (int cf = 0; cf < 4; ++cf) {
      const int bl = cf * 16 + c;
      bf16x8 B0h = *(const bf16x8*)&Bhs[bl][kg * 8];
      bf16x8 B1h = *(const bf16x8*)&Bhs[bl][kg * 8 + 32];
      bf16x8 B0l = *(const bf16x8*)&Bls[bl][kg * 8];
      bf16x8 B1l = *(const bf16x8*)&Bls[bl][kg * 8 + 32];
      f32x4 a = {0.f, 0.f, 0.f, 0.f};
      a = MFMA16(A0h, B0h, a);
      a = MFMA16(A0h, B0l, a);
      a = MFMA16(A0l, B0h, a);
      a = MFMA16(A1h, B1h, a);
      a = MFMA16(A1h, B1l, a);
      a = MFMA16(A1l, B1h, a);
      acc[cf] = a;
    }
    float X[4][4];
#pragma unroll
    for (int cf = 0; cf < 4; ++cf) {
      const int col = b0 + cf * 16 + c;
      const float vb2 = din_s[col];
      const float y2  = y2_s[col];
#pragma unroll
      for (int r = 0; r < 4; ++r) {
        float d2 = fmaf(-2.f, acc[cf][r], x2r[r] + y2);
        float sq = fast_sqrt(fmaxf(d2, 0.f));
        X[cf][r] = fmaf(-IEL2, sq, vb2);
      }
    }
#pragma unroll
    for (int r = 0; r < 4; ++r) {
      float m1 = max3f(X[0][r], X[1][r], X[2][r]);
      float nm = max3f(m1, X[3][r], M[r]);
      float s4 = fast_exp2(X[0][r] - nm) + fast_exp2(X[1][r] - nm)
               + fast_exp2(X[2][r] - nm) + fast_exp2(X[3][r] - nm);
      S[r] = fmaf(S[r], fast_exp2(M[r] - nm), s4);
      M[r] = nm;
    }
  }
  // combine across the 16 col-lanes
#pragma unroll
  for (int off = 1; off <= 8; off <<= 1) {
#pragma unroll
    for (int r = 0; r < 4; ++r) {
      float Mo = __shfl_xor(M[r], off);
      float So = __shfl_xor(S[r], off);
      float nm = fmaxf(M[r], Mo);
      S[r] = S[r] * fast_exp2(M[r] - nm) + So * fast_exp2(Mo - nm);
      M[r] = nm;
    }
  }
  if (c == 0) {
#pragma unroll
    for (int r = 0; r < 4; ++r)
      dout[(size_t)m * NN + arow + kg * 4 + r] =
          LOG_A - M[r] * LN2F - __logf(S[r]);
  }
}

// ---------------------------------------------------------------------------
// K3: MFMA PV pass. Two-phase PV per tile (halved pT), truncating stores.
// ---------------------------------------------------------------------------
__global__ __launch_bounds__(256) void k_pv_mfma(
    const u16* __restrict__ qh, const u16* __restrict__ ql,
    const u16* __restrict__ kh, const u16* __restrict__ kl,
    const u16* __restrict__ vT, const float* __restrict__ qn,
    const float* __restrict__ kn, const float* __restrict__ ue,
    const float* __restrict__ ve, u16* __restrict__ Oh_, u16* __restrict__ Ol_)
{
  __shared__ __align__(16) float ve_s[NN];   // pre-scaled by log2(e)
  __shared__ __align__(16) float y2_s[NN];
  __shared__ __align__(16) u16 Bhs[64][72];
  __shared__ __align__(16) u16 Bls[64][72];
  __shared__ __align__(16) u16 Vs[64][72];
  __shared__ __align__(16) u16 pT[4][16][40];   // half-width P strip per wave
  const int t = threadIdx.x;
  const int Lb = blockIdx.x;
  const int xcd = Lb & 7, slot = Lb >> 3;
  const int m = xcd + 8 * (slot >> 4);
  const int a0 = (slot & 15) * 64;
  {
    float4 vv = *(const float4*)&ve[(size_t)m * NN + t * 4];
    vv.x *= L2E; vv.y *= L2E; vv.z *= L2E; vv.w *= L2E;
    *(float4*)&ve_s[t * 4] = vv;
  }
  *(float4*)&y2_s[t * 4] = *(const float4*)&kn[(size_t)m * NN + t * 4];

  const int w = t >> 6, l = t & 63;
  const int c = l & 15, kg = l >> 4;
  const int arow = a0 + w * 16;
  const size_t mbase = (size_t)m * NN * NDS;

  const u16* pah = &qh[mbase + (size_t)(arow + c) * NDS + kg * 8];
  const u16* pal = &ql[mbase + (size_t)(arow + c) * NDS + kg * 8];
  bf16x8 A0h = *(const bf16x8*)pah;
  bf16x8 A1h = *(const bf16x8*)(pah + 32);
  bf16x8 A0l = *(const bf16x8*)pal;
  bf16x8 A1l = *(const bf16x8*)(pal + 32);

  float x2r[4], uer2[4];
#pragma unroll
  for (int r = 0; r < 4; ++r) {
    x2r[r]  = qn[(size_t)m * NN + arow + kg * 4 + r];
    uer2[r] = ue[(size_t)m * NN + arow + kg * 4 + r] * L2E;
  }
  f32x4 pacc[4];
#pragma unroll
  for (int df = 0; df < 4; ++df) pacc[df] = (f32x4){0.f, 0.f, 0.f, 0.f};

  const int srow = t >> 2;
  const int skoff = (t & 3) * 16;
  const u16* gh = &kh[mbase + (size_t)srow * NDS + skoff];
  const u16* gl = &kl[mbase + (size_t)srow * NDS + skoff];
  const u16* gv = &vT[((size_t)m * NDS + srow) * NN + skoff];
  bf16x8 rh0 = *(const bf16x8*)gh, rh1 = *(const bf16x8*)(gh + 8);
  bf16x8 rl0 = *(const bf16x8*)gl, rl1 = *(const bf16x8*)(gl + 8);
  bf16x8 rv0 = *(const bf16x8*)gv, rv1 = *(const bf16x8*)(gv + 8);

  for (int bt = 0; bt < 16; ++bt) {
    const int b0 = bt * 64;
    __syncthreads();
    *(bf16x8*)&Bhs[srow][skoff]     = rh0;
    *(bf16x8*)&Bhs[srow][skoff + 8] = rh1;
    *(bf16x8*)&Bls[srow][skoff]     = rl0;
    *(bf16x8*)&Bls[srow][skoff + 8] = rl1;
    *(bf16x8*)&Vs[srow][skoff]      = rv0;
    *(bf16x8*)&Vs[srow][skoff + 8]  = rv1;
    {
      const int nbt = (bt + 1) & 15;
      const size_t nk = (size_t)nbt * 4096;   // K tiles: 64 rows * 64
      const size_t nv = (size_t)nbt * 64;     // V^T tiles: +64 columns
      rh0 = *(const bf16x8*)(gh + nk);
      rh1 = *(const bf16x8*)(gh + nk + 8);
      rl0 = *(const bf16x8*)(gl + nk);
      rl1 = *(const bf16x8*)(gl + nk + 8);
      rv0 = *(const bf16x8*)(gv + nv);
      rv1 = *(const bf16x8*)(gv + nv + 8);
    }
    __syncthreads();
    // two phases: j-half 0 (cf 0..1) then j-half 1 (cf 2..3)
#pragma unroll
    for (int ph = 0; ph < 2; ++ph) {
      f32x4 acc[2];
#pragma unroll
      for (int q = 0; q < 2; ++q) {
        const int cf = ph * 2 + q;
        const int bl = cf * 16 + c;
        bf16x8 B0h = *(const bf16x8*)&Bhs[bl][kg * 8];
        bf16x8 B1h = *(const bf16x8*)&Bhs[bl][kg * 8 + 32];
        bf16x8 B0l = *(const bf16x8*)&Bls[bl][kg * 8];
        bf16x8 B1l = *(const bf16x8*)&Bls[bl][kg * 8 + 32];
        f32x4 a = {0.f, 0.f, 0.f, 0.f};
        a = MFMA16(A0h, B0h, a);
        a = MFMA16(A0h, B0l, a);
        a = MFMA16(A0l, B0h, a);
        a = MFMA16(A1h, B1h, a);
        a = MFMA16(A1h, B1l, a);
        a = MFMA16(A1l, B1h, a);
        acc[q] = a;
      }
#pragma unroll
      for (int q = 0; q < 2; ++q) {
        const int cf = ph * 2 + q;
        const int col = b0 + cf * 16 + c;
        const float ve2 = ve_s[col];
        const float y2  = y2_s[col];
#pragma unroll
        for (int r = 0; r < 4; ++r) {
          float d2 = fmaf(-2.f, acc[q][r], x2r[r] + y2);
          float sq = fast_sqrt(fmaxf(d2, 0.f));
          float p  = fast_exp2(fmaf(-IEL2, sq, uer2[r] + ve2));
          pT[w][kg * 4 + r][q * 16 + c] = f2bf_t(p);
        }
      }
      bf16x8 Pa = *(const bf16x8*)&pT[w][c][kg * 8];
#pragma unroll
      for (int df = 0; df < 4; ++df) {
        bf16x8 Vb = *(const bf16x8*)&Vs[df * 16 + c][ph * 32 + kg * 8];
        pacc[df] = MFMA16(Pa, Vb, pacc[df]);
      }
    }
  }
  // epilogue: O = SQRT_V * q + pacc, stored as bf16 hi/lo (truncating)
#pragma unroll
  for (int df = 0; df < 4; ++df) {
#pragma unroll
    for (int r = 0; r < 4; ++r) {
      int row = arow + kg * 4 + r;
      int d = df * 16 + c;
      size_t qi = mbase + (size_t)row * NDS + d;
      float qv = bf2f(qh[qi]) + bf2f(ql[qi]);
      float o  = fmaf(SQRT_V, qv, pacc[df][r]);
      u16 hv = f2bf_t(o);
      Oh_[qi] = hv;
      Ol_[qi] = f2bf_t(o - bf2f(hv));
    }
  }
}

// ---------------------------------------------------------------------------
// K4: MFMA output GEMM (round-5 structure).
// ---------------------------------------------------------------------------
__global__ __launch_bounds__(256) void k_out_mfma(
    const u16* __restrict__ Oh_, const u16* __restrict__ Ol_,
    const u16* __restrict__ Wh, const u16* __restrict__ Wl,
    const float* __restrict__ bo, float* __restrict__ out)
{
  __shared__ __align__(16) u16 Ahs[64][72];
  __shared__ __align__(16) u16 Als[64][72];
  __shared__ __align__(16) u16 Whs[64][72];
  __shared__ __align__(16) u16 Wls[64][72];
  const int t = threadIdx.x;
  const int r0 = blockIdx.x * 64;
  const int c0 = blockIdx.y * 64;
  const int bb = r0 >> 10;
  const int n0 = r0 & 1023;
  const int w = t >> 6, l = t & 63;
  const int c = l & 15, kg = l >> 4;
  const int srow = t >> 2;
  const int skoff = (t & 3) * 16;

  f32x4 acc[4];
#pragma unroll
  for (int cf = 0; cf < 4; ++cf) acc[cf] = (f32x4){0.f, 0.f, 0.f, 0.f};

  for (int kt = 0; kt < 8; ++kt) {
    __syncthreads();
    {
      const size_t ob = ((size_t)(kt * NB + bb) * NN + n0 + srow) * NDS;
      const u16* gah = &Oh_[ob + skoff];
      const u16* gal = &Ol_[ob + skoff];
      const u16* gwh = &Wh[(size_t)(c0 + srow) * ND + kt * 64 + skoff];
      const u16* gwl = &Wl[(size_t)(c0 + srow) * ND + kt * 64 + skoff];
      *(bf16x8*)&Ahs[srow][skoff]     = *(const bf16x8*)gah;
      *(bf16x8*)&Ahs[srow][skoff + 8] = *(const bf16x8*)(gah + 8);
      *(bf16x8*)&Als[srow][skoff]     = *(const bf16x8*)gal;
      *(bf16x8*)&Als[srow][skoff + 8] = *(const bf16x8*)(gal + 8);
      *(bf16x8*)&Whs[srow][skoff]     = *(const bf16x8*)gwh;
      *(bf16x8*)&Whs[srow][skoff + 8] = *(const bf16x8*)(gwh + 8);
      *(bf16x8*)&Wls[srow][skoff]     = *(const bf16x8*)gwl;
      *(bf16x8*)&Wls[srow][skoff + 8] = *(const bf16x8*)(gwl + 8);
    }
    __syncthreads();
#pragma unroll
    for (int ks = 0; ks < 2; ++ks) {
      bf16x8 Ah = *(const bf16x8*)&Ahs[w * 16 + c][ks * 32 + kg * 8];
      bf16x8 Al = *(const bf16x8*)&Als[w * 16 + c][ks * 32 + kg * 8];
#pragma unroll
      for (int cf = 0; cf < 4; ++cf) {
        bf16x8 Bh = *(const bf16x8*)&Whs[cf * 16 + c][ks * 32 + kg * 8];
        bf16x8 Bl = *(const bf16x8*)&Wls[cf * 16 + c][ks * 32 + kg * 8];
        acc[cf] = MFMA16(Ah, Bh, acc[cf]);
        acc[cf] = MFMA16(Ah, Bl, acc[cf]);
        acc[cf] = MFMA16(Al, Bh, acc[cf]);
      }
    }
  }
#pragma unroll
  for (int cf = 0; cf < 4; ++cf) {
    const int col = c0 + cf * 16 + c;
    const int d = cf * 16 + c;
    const float bv = bo[col];
#pragma unroll
    for (int r = 0; r < 4; ++r) {
      const int n = n0 + w * 16 + kg * 4 + r;
      const size_t oi = ((size_t)(blockIdx.y * NB + bb) * NN + n) * NDS + d;
      float om = bf2f(Oh_[oi]) + bf2f(Ol_[oi]);
      out[(size_t)(r0 + w * 16 + kg * 4 + r) * ND + col] =
          om + fmaxf(acc[cf][r] + bv, 0.f);
    }
  }
}

// ---------------------------------------------------------------------------
extern "C" void kernel_launch(void* const* d_in, const int* in_sizes, int n_in,
                              void* d_out, int out_size, void* d_ws, size_t ws_size,
                              hipStream_t stream) {
  const float* Q  = (const float*)d_in[0];
  const float* K  = (const float*)d_in[1];
  const float* Wq = (const float*)d_in[2];
  const float* bq = (const float*)d_in[3];
  const float* Wk = (const float*)d_in[4];
  const float* bk = (const float*)d_in[5];
  const float* Wv = (const float*)d_in[6];
  const float* bv = (const float*)d_in[7];
  const float* Wo = (const float*)d_in[8];
  const float* bo = (const float*)d_in[9];
  float* out = (float*)d_out;

  const size_t need_bytes =
      7 * SPLIT_ELEMS * sizeof(u16) + 8 * W_ELEMS * sizeof(u16) +
      4 * UV_FLOATS * sizeof(float);
  if (ws_size < need_bytes) return;

  u16* qh = (u16*)d_ws;
  u16* ql = qh + SPLIT_ELEMS;
  u16* kh = ql + SPLIT_ELEMS;
  u16* kl = kh + SPLIT_ELEMS;
  u16* vT = kl + SPLIT_ELEMS;
  u16* Oh = vT + SPLIT_ELEMS;     // phase 1-2: raw Q split; phase 3+: O hi
  u16* Ol = Oh + SPLIT_ELEMS;
  u16* wqh = Ol + SPLIT_ELEMS;
  u16* wql = wqh + W_ELEMS;
  u16* wkh = wql + W_ELEMS;
  u16* wkl = wkh + W_ELEMS;
  u16* wvh = wkl + W_ELEMS;
  u16* wvl = wvh + W_ELEMS;
  u16* woh = wvl + W_ELEMS;
  u16* wol = woh + W_ELEMS;
  float* ue = (float*)(wol + W_ELEMS);
  float* ve = ue + UV_FLOATS;
  float* qn = ve + UV_FLOATS;
  float* kn = qn + UV_FLOATS;

  u16* Qrh = Oh;                  // aliased raw input splits
  u16* Qrl = Ol;
  u16* Krh = (u16*)d_out;         // d_out fully overwritten at end
  u16* Krl = Krh + SPLIT_ELEMS;

  dim3 blk(256);
  k_split<<<dim3(4096), blk, 0, stream>>>(Q, Qrh, Qrl);
  k_split<<<dim3(4096), blk, 0, stream>>>(K, Krh, Krl);
  k_split<<<dim3(256), blk, 0, stream>>>(Wq, wqh, wql);
  k_split<<<dim3(256), blk, 0, stream>>>(Wk, wkh, wkl);
  k_split<<<dim3(256), blk, 0, stream>>>(Wv, wvh, wvl);
  k_split<<<dim3(256), blk, 0, stream>>>(Wo, woh, wol);
  k_proj_mfma<<<dim3(128, 8), blk, 0, stream>>>(Qrh, Qrl, wqh, wql, bq, qh, ql, nullptr, qn, INV_SQRT_V, 0);
  k_proj_mfma<<<dim3(128, 8), blk, 0, stream>>>(Krh, Krl, wkh, wkl, bk, kh, kl, nullptr, kn, INV_SQRT_V, 0);
  k_proj_mfma<<<dim3(128, 8), blk, 0, stream>>>(Krh, Krl, wvh, wvl, bv, nullptr, nullptr, vT, nullptr, 1.0f, 1);
  for (int it = 0; it < 3; ++it) {
    k_lse_mfma<<<dim3(512), dim3(512), 0, stream>>>(qh, ql, kh, kl, qn, kn, ve, ue, it == 0 ? 1 : 0);
    k_lse_mfma<<<dim3(512), dim3(512), 0, stream>>>(kh, kl, qh, ql, kn, qn, ue, ve, 0);
  }
  k_pv_mfma<<<dim3(1024), blk, 0, stream>>>(qh, ql, kh, kl, vT, qn, kn, ue, ve, Oh, Ol);
  k_out_mfma<<<dim3(128, 8), blk, 0, stream>>>(Oh, Ol, woh, wol, bo, out);
}

// Round 8
// 373.224 us; speedup vs baseline: 4.5975x; 1.0188x over previous
//
#include <hip/hip_runtime.h>
#include <hip/hip_bf16.h>
#include <math.h>

// Problem constants
#define NB 8          // batch
#define NN 1024       // NQ = NK
#define ND 512        // DQ = DK = DV
#define NH 8          // heads
#define NDS 64        // head dim
#define NM 64         // NH * NB
#define LOG_A (-6.93147180559945f)     // -log(1024)
#define SQRT_V 4.75682846001088f       // 512^0.25
#define INV_SQRT_V 0.210224103813429f
#define INV_EPS 10000.0f               // 1/EPS
#define L2E  1.44269504088896f         // log2(e)
#define LN2F 0.693147180559945f
#define IEL2 14426.9504088896f         // INV_EPS * log2(e)

#define SPLIT_ELEMS ((size_t)NM * NN * NDS)   // 4,194,304 u16 (8 MB)
#define W_ELEMS     ((size_t)ND * ND)         // 262,144
#define UV_FLOATS   ((size_t)NM * NN)

typedef unsigned short u16;
typedef unsigned int   u32;
typedef __attribute__((ext_vector_type(8))) short bf16x8;   // 8 bf16 = 4 VGPR
typedef __attribute__((ext_vector_type(4))) float f32x4;

#define MFMA16(a,b,c) __builtin_amdgcn_mfma_f32_16x16x32_bf16(a,b,c,0,0,0)

__device__ __forceinline__ u16 f2bf_t(float x) {    // truncating float->bf16
  return (u16)(__float_as_uint(x) >> 16);
}
__device__ __forceinline__ float bf2f(u16 h) {
  return __uint_as_float(((u32)h) << 16);
}
__device__ __forceinline__ float fast_sqrt(float x) {   // v_sqrt_f32
  float r;
  asm("v_sqrt_f32 %0, %1" : "=v"(r) : "v"(x));
  return r;
}
__device__ __forceinline__ float fast_exp2(float x) {   // v_exp_f32 = 2^x
  float r;
  asm("v_exp_f32 %0, %1" : "=v"(r) : "v"(x));
  return r;
}
__device__ __forceinline__ float max3f(float a, float b, float c) {
  float r;
  asm("v_max3_f32 %0, %1, %2, %3" : "=v"(r) : "v"(a), "v"(b), "v"(c));
  return r;
}

// ---------------------------------------------------------------------------
// K0: elementwise f32 -> bf16 hi/lo split (truncating).
// ---------------------------------------------------------------------------
__global__ __launch_bounds__(256) void k_split(
    const float* __restrict__ X, u16* __restrict__ hi, u16* __restrict__ lo)
{
  const size_t i = ((size_t)blockIdx.x * 256 + threadIdx.x) * 4;
  float4 v = *(const float4*)&X[i];
  const float* vp = (const float*)&v;
  u16 h[4], l[4];
#pragma unroll
  for (int j = 0; j < 4; ++j) {
    h[j] = f2bf_t(vp[j]);
    l[j] = f2bf_t(vp[j] - bf2f(h[j]));
  }
  uint2 ph, pl;
  ph.x = (u32)h[0] | ((u32)h[1] << 16);
  ph.y = (u32)h[2] | ((u32)h[3] << 16);
  pl.x = (u32)l[0] | ((u32)l[1] << 16);
  pl.y = (u32)l[2] | ((u32)l[3] << 16);
  *(uint2*)&hi[i] = ph;
  *(uint2*)&lo[i] = pl;
}

// ---------------------------------------------------------------------------
// K1: MFMA projection (round-5 structure; truncating epilogue).
// ---------------------------------------------------------------------------
__global__ __launch_bounds__(256) void k_proj_mfma(
    const u16* __restrict__ Xh, const u16* __restrict__ Xl,
    const u16* __restrict__ Wh, const u16* __restrict__ Wl,
    const float* __restrict__ bias, u16* __restrict__ oh,
    u16* __restrict__ ol, u16* __restrict__ oT,
    float* __restrict__ nrm, float scale, int mode)
{
  __shared__ __align__(16) u16 Xhs[64][72];
  __shared__ __align__(16) u16 Xls[64][72];
  __shared__ __align__(16) u16 Whs[64][72];
  __shared__ __align__(16) u16 Wls[64][72];
  const int t = threadIdx.x;
  const int r0 = blockIdx.x * 64;
  const int h  = blockIdx.y;
  const int c0 = h * 64;
  const int w = t >> 6, l = t & 63;
  const int c = l & 15, kg = l >> 4;
  const int srow = t >> 2;
  const int skoff = (t & 3) * 16;

  f32x4 acc[4];
#pragma unroll
  for (int cf = 0; cf < 4; ++cf) acc[cf] = (f32x4){0.f, 0.f, 0.f, 0.f};

  for (int kt = 0; kt < 8; ++kt) {
    const int k0 = kt * 64;
    __syncthreads();
    {
      const u16* gxh = &Xh[(size_t)(r0 + srow) * ND + k0 + skoff];
      const u16* gxl = &Xl[(size_t)(r0 + srow) * ND + k0 + skoff];
      const u16* gwh = &Wh[(size_t)(c0 + srow) * ND + k0 + skoff];
      const u16* gwl = &Wl[(size_t)(c0 + srow) * ND + k0 + skoff];
      *(bf16x8*)&Xhs[srow][skoff]     = *(const bf16x8*)gxh;
      *(bf16x8*)&Xhs[srow][skoff + 8] = *(const bf16x8*)(gxh + 8);
      *(bf16x8*)&Xls[srow][skoff]     = *(const bf16x8*)gxl;
      *(bf16x8*)&Xls[srow][skoff + 8] = *(const bf16x8*)(gxl + 8);
      *(bf16x8*)&Whs[srow][skoff]     = *(const bf16x8*)gwh;
      *(bf16x8*)&Whs[srow][skoff + 8] = *(const bf16x8*)(gwh + 8);
      *(bf16x8*)&Wls[srow][skoff]     = *(const bf16x8*)gwl;
      *(bf16x8*)&Wls[srow][skoff + 8] = *(const bf16x8*)(gwl + 8);
    }
    __syncthreads();
#pragma unroll
    for (int ks = 0; ks < 2; ++ks) {
      bf16x8 Ah = *(const bf16x8*)&Xhs[w * 16 + c][ks * 32 + kg * 8];
      bf16x8 Al = *(const bf16x8*)&Xls[w * 16 + c][ks * 32 + kg * 8];
#pragma unroll
      for (int cf = 0; cf < 4; ++cf) {
        bf16x8 Bh = *(const bf16x8*)&Whs[cf * 16 + c][ks * 32 + kg * 8];
        bf16x8 Bl = *(const bf16x8*)&Wls[cf * 16 + c][ks * 32 + kg * 8];
        acc[cf] = MFMA16(Ah, Bh, acc[cf]);
        acc[cf] = MFMA16(Ah, Bl, acc[cf]);
        acc[cf] = MFMA16(Al, Bh, acc[cf]);
      }
    }
  }

  const int bb = r0 >> 10;
  const int n0 = r0 & 1023;
  const size_t mrow = (size_t)(h * NB + bb) * NN;
  if (mode == 0) {
    float ns[4] = {0.f, 0.f, 0.f, 0.f};
#pragma unroll
    for (int cf = 0; cf < 4; ++cf) {
      const int col = c0 + cf * 16 + c;
      const float bv = bias[col];
#pragma unroll
      for (int r = 0; r < 4; ++r) {
        float v = (acc[cf][r] + bv) * scale;
        u16 hv = f2bf_t(v);
        u16 lv = f2bf_t(v - bf2f(hv));
        ns[r] = fmaf(v, v, ns[r]);
        int n = n0 + w * 16 + kg * 4 + r;
        size_t idx = (mrow + n) * NDS + cf * 16 + c;
        oh[idx] = hv;
        ol[idx] = lv;
      }
    }
#pragma unroll
    for (int off = 1; off <= 8; off <<= 1)
#pragma unroll
      for (int r = 0; r < 4; ++r) ns[r] += __shfl_xor(ns[r], off);
    if (c == 0) {
#pragma unroll
      for (int r = 0; r < 4; ++r)
        nrm[mrow + n0 + w * 16 + kg * 4 + r] = ns[r];
    }
  } else {
#pragma unroll
    for (int cf = 0; cf < 4; ++cf) {
      const int d = cf * 16 + c;
      const float bv = bias[c0 + d];
      u16 p0 = f2bf_t((acc[cf][0] + bv) * scale);
      u16 p1 = f2bf_t((acc[cf][1] + bv) * scale);
      u16 p2 = f2bf_t((acc[cf][2] + bv) * scale);
      u16 p3 = f2bf_t((acc[cf][3] + bv) * scale);
      uint2 p;
      p.x = (u32)p0 | ((u32)p1 << 16);
      p.y = (u32)p2 | ((u32)p3 << 16);
      *(uint2*)&oT[((size_t)(h * NB + bb) * NDS + d) * NN + n0 + w * 16 + kg * 4] = p;
    }
  }
}

// ---------------------------------------------------------------------------
// K2: MFMA LSE pass. 512 threads / 8 waves; double-buffered LDS, ONE barrier
// per tile; log2-domain flash; max3; XCD-grouped.
// ---------------------------------------------------------------------------
__global__ __launch_bounds__(512, 4) void k_lse_mfma(
    const u16* __restrict__ Ah_, const u16* __restrict__ Al_,
    const u16* __restrict__ Bh_, const u16* __restrict__ Bl_,
    const float* __restrict__ Anrm, const float* __restrict__ Bnrm,
    const float* __restrict__ din, float* __restrict__ dout, int first)
{
  __shared__ __align__(16) float din_s[NN];   // pre-scaled by log2(e)
  __shared__ __align__(16) float y2_s[NN];
  __shared__ __align__(16) u16 Bhs[2][64][72];
  __shared__ __align__(16) u16 Bls[2][64][72];
  const int t = threadIdx.x;
  const int Lb = blockIdx.x;                  // 512 blocks
  const int xcd = Lb & 7, slot = Lb >> 3;     // slot 0..63
  const int m = xcd + 8 * (slot >> 3);
  const int a0 = (slot & 7) * 128;

  if (first) {
    *(float2*)&din_s[t * 2] = make_float2(0.f, 0.f);
  } else {
    float2 dv = *(const float2*)&din[(size_t)m * NN + t * 2];
    dv.x *= L2E; dv.y *= L2E;
    *(float2*)&din_s[t * 2] = dv;
  }
  *(float2*)&y2_s[t * 2] = *(const float2*)&Bnrm[(size_t)m * NN + t * 2];

  const int w = t >> 6, l = t & 63;
  const int c = l & 15, kg = l >> 4;
  const int arow = a0 + w * 16;
  const size_t mbase = (size_t)m * NN * NDS;

  const u16* pah = &Ah_[mbase + (size_t)(arow + c) * NDS + kg * 8];
  const u16* pal = &Al_[mbase + (size_t)(arow + c) * NDS + kg * 8];
  bf16x8 A0h = *(const bf16x8*)pah;
  bf16x8 A1h = *(const bf16x8*)(pah + 32);
  bf16x8 A0l = *(const bf16x8*)pal;
  bf16x8 A1l = *(const bf16x8*)(pal + 32);

  float x2r[4];
#pragma unroll
  for (int r = 0; r < 4; ++r) x2r[r] = Anrm[(size_t)m * NN + arow + kg * 4 + r];
  float M[4], S[4];
#pragma unroll
  for (int r = 0; r < 4; ++r) { M[r] = -3.0e38f; S[r] = 0.f; }

  const int srow = t >> 3;            // 0..63
  const int skoff = (t & 7) * 8;      // 8 u16 per thread per buffer
  const u16* gh = &Bh_[mbase + (size_t)srow * NDS + skoff];
  const u16* gl = &Bl_[mbase + (size_t)srow * NDS + skoff];
  bf16x8 rh = *(const bf16x8*)gh;
  bf16x8 rl = *(const bf16x8*)gl;

  for (int bt = 0; bt < 16; ++bt) {
    const int b0 = bt * 64;
    const int buf = bt & 1;
    *(bf16x8*)&Bhs[buf][srow][skoff] = rh;
    *(bf16x8*)&Bls[buf][srow][skoff] = rl;
    {   // prefetch next tile (wraps harmlessly at bt=15)
      const size_t noff = (size_t)((bt + 1) & 15) * 4096;
      rh = *(const bf16x8*)(gh + noff);
      rl = *(const bf16x8*)(gl + noff);
    }
    __syncthreads();                 // writes visible; prev buffer free
    f32x4 acc[4];
#pragma unroll
    for (int cf = 0; cf < 4; ++cf) {
      const int bl = cf * 16 + c;
      bf16x8 B0h = *(const bf16x8*)&Bhs[buf][bl][kg * 8];
      bf16x8 B1h = *(const bf16x8*)&Bhs[buf][bl][kg * 8 + 32];
      bf16x8 B0l = *(const bf16x8*)&Bls[buf][bl][kg * 8];
      bf16x8 B1l = *(const bf16x8*)&Bls[buf][bl][kg * 8 + 32];
      f32x4 a = {0.f, 0.f, 0.f, 0.f};
      a = MFMA16(A0h, B0h, a);
      a = MFMA16(A0h, B0l, a);
      a = MFMA16(A0l, B0h, a);
      a = MFMA16(A1h, B1h, a);
      a = MFMA16(A1h, B1l, a);
      a = MFMA16(A1l, B1h, a);
      acc[cf] = a;
    }
    float X[4][4];
#pragma unroll
    for (int cf = 0; cf < 4; ++cf) {
      const int col = b0 + cf * 16 + c;
      const float vb2 = din_s[col];
      const float y2  = y2_s[col];
#pragma unroll
      for (int r = 0; r < 4; ++r) {
        float d2 = fmaf(-2.f, acc[cf][r], x2r[r] + y2);
        float sq = fast_sqrt(fmaxf(d2, 0.f));
        X[cf][r] = fmaf(-IEL2, sq, vb2);
      }
    }
#pragma unroll
    for (int r = 0; r < 4; ++r) {
      float m1 = max3f(X[0][r], X[1][r], X[2][r]);
      float nm = max3f(m1, X[3][r], M[r]);
      float s4 = fast_exp2(X[0][r] - nm) + fast_exp2(X[1][r] - nm)
               + fast_exp2(X[2][r] - nm) + fast_exp2(X[3][r] - nm);
      S[r] = fmaf(S[r], fast_exp2(M[r] - nm), s4);
      M[r] = nm;
    }
  }
  // combine across the 16 col-lanes
#pragma unroll
  for (int off = 1; off <= 8; off <<= 1) {
#pragma unroll
    for (int r = 0; r < 4; ++r) {
      float Mo = __shfl_xor(M[r], off);
      float So = __shfl_xor(S[r], off);
      float nm = fmaxf(M[r], Mo);
      S[r] = S[r] * fast_exp2(M[r] - nm) + So * fast_exp2(Mo - nm);
      M[r] = nm;
    }
  }
  if (c == 0) {
#pragma unroll
    for (int r = 0; r < 4; ++r)
      dout[(size_t)m * NN + arow + kg * 4 + r] =
          LOG_A - M[r] * LN2F - __logf(S[r]);
  }
}

// ---------------------------------------------------------------------------
// K3: MFMA PV pass. 512 threads / 8 waves; double-buffered LDS, ONE barrier
// per tile; per-wave private pT strips; two-phase PV; truncating stores.
// ---------------------------------------------------------------------------
__global__ __launch_bounds__(512, 4) void k_pv_mfma(
    const u16* __restrict__ qh, const u16* __restrict__ ql,
    const u16* __restrict__ kh, const u16* __restrict__ kl,
    const u16* __restrict__ vT, const float* __restrict__ qn,
    const float* __restrict__ kn, const float* __restrict__ ue,
    const float* __restrict__ ve, u16* __restrict__ Oh_, u16* __restrict__ Ol_)
{
  __shared__ __align__(16) float ve_s[NN];   // pre-scaled by log2(e)
  __shared__ __align__(16) float y2_s[NN];
  __shared__ __align__(16) u16 Bhs[2][64][72];
  __shared__ __align__(16) u16 Bls[2][64][72];
  __shared__ __align__(16) u16 Vs[2][64][72];
  __shared__ __align__(16) u16 pT[8][16][40];   // per-wave private
  const int t = threadIdx.x;
  const int Lb = blockIdx.x;                  // 512 blocks
  const int xcd = Lb & 7, slot = Lb >> 3;     // slot 0..63
  const int m = xcd + 8 * (slot >> 3);
  const int a0 = (slot & 7) * 128;
  {
    float2 vv = *(const float2*)&ve[(size_t)m * NN + t * 2];
    vv.x *= L2E; vv.y *= L2E;
    *(float2*)&ve_s[t * 2] = vv;
  }
  *(float2*)&y2_s[t * 2] = *(const float2*)&kn[(size_t)m * NN + t * 2];

  const int w = t >> 6, l = t & 63;
  const int c = l & 15, kg = l >> 4;
  const int arow = a0 + w * 16;
  const size_t mbase = (size_t)m * NN * NDS;

  const u16* pah = &qh[mbase + (size_t)(arow + c) * NDS + kg * 8];
  const u16* pal = &ql[mbase + (size_t)(arow + c) * NDS + kg * 8];
  bf16x8 A0h = *(const bf16x8*)pah;
  bf16x8 A1h = *(const bf16x8*)(pah + 32);
  bf16x8 A0l = *(const bf16x8*)pal;
  bf16x8 A1l = *(const bf16x8*)(pal + 32);

  float x2r[4], uer2[4];
#pragma unroll
  for (int r = 0; r < 4; ++r) {
    x2r[r]  = qn[(size_t)m * NN + arow + kg * 4 + r];
    uer2[r] = ue[(size_t)m * NN + arow + kg * 4 + r] * L2E;
  }
  f32x4 pacc[4];
#pragma unroll
  for (int df = 0; df < 4; ++df) pacc[df] = (f32x4){0.f, 0.f, 0.f, 0.f};

  const int srow = t >> 3;            // 0..63
  const int skoff = (t & 7) * 8;      // one bf16x8 per thread per buffer
  const u16* gh = &kh[mbase + (size_t)srow * NDS + skoff];
  const u16* gl = &kl[mbase + (size_t)srow * NDS + skoff];
  const u16* gv = &vT[((size_t)m * NDS + srow) * NN + skoff];
  bf16x8 rh = *(const bf16x8*)gh;
  bf16x8 rl = *(const bf16x8*)gl;
  bf16x8 rv = *(const bf16x8*)gv;

  for (int bt = 0; bt < 16; ++bt) {
    const int b0 = bt * 64;
    const int buf = bt & 1;
    *(bf16x8*)&Bhs[buf][srow][skoff] = rh;
    *(bf16x8*)&Bls[buf][srow][skoff] = rl;
    *(bf16x8*)&Vs[buf][srow][skoff]  = rv;
    {
      const int nbt = (bt + 1) & 15;
      rh = *(const bf16x8*)(gh + (size_t)nbt * 4096);
      rl = *(const bf16x8*)(gl + (size_t)nbt * 4096);
      rv = *(const bf16x8*)(gv + (size_t)nbt * 64);
    }
    __syncthreads();
    // two phases: j-half 0 (cf 0..1) then j-half 1 (cf 2..3)
#pragma unroll
    for (int ph = 0; ph < 2; ++ph) {
      f32x4 acc[2];
#pragma unroll
      for (int q = 0; q < 2; ++q) {
        const int cf = ph * 2 + q;
        const int bl = cf * 16 + c;
        bf16x8 B0h = *(const bf16x8*)&Bhs[buf][bl][kg * 8];
        bf16x8 B1h = *(const bf16x8*)&Bhs[buf][bl][kg * 8 + 32];
        bf16x8 B0l = *(const bf16x8*)&Bls[buf][bl][kg * 8];
        bf16x8 B1l = *(const bf16x8*)&Bls[buf][bl][kg * 8 + 32];
        f32x4 a = {0.f, 0.f, 0.f, 0.f};
        a = MFMA16(A0h, B0h, a);
        a = MFMA16(A0h, B0l, a);
        a = MFMA16(A0l, B0h, a);
        a = MFMA16(A1h, B1h, a);
        a = MFMA16(A1h, B1l, a);
        a = MFMA16(A1l, B1h, a);
        acc[q] = a;
      }
#pragma unroll
      for (int q = 0; q < 2; ++q) {
        const int cf = ph * 2 + q;
        const int col = b0 + cf * 16 + c;
        const float ve2 = ve_s[col];
        const float y2  = y2_s[col];
#pragma unroll
        for (int r = 0; r < 4; ++r) {
          float d2 = fmaf(-2.f, acc[q][r], x2r[r] + y2);
          float sq = fast_sqrt(fmaxf(d2, 0.f));
          float p  = fast_exp2(fmaf(-IEL2, sq, uer2[r] + ve2));
          pT[w][kg * 4 + r][q * 16 + c] = f2bf_t(p);
        }
      }
      bf16x8 Pa = *(const bf16x8*)&pT[w][c][kg * 8];
#pragma unroll
      for (int df = 0; df < 4; ++df) {
        bf16x8 Vb = *(const bf16x8*)&Vs[buf][df * 16 + c][ph * 32 + kg * 8];
        pacc[df] = MFMA16(Pa, Vb, pacc[df]);
      }
    }
  }
  // epilogue: O = SQRT_V * q + pacc, stored as bf16 hi/lo (truncating)
#pragma unroll
  for (int df = 0; df < 4; ++df) {
#pragma unroll
    for (int r = 0; r < 4; ++r) {
      int row = arow + kg * 4 + r;
      int d = df * 16 + c;
      size_t qi = mbase + (size_t)row * NDS + d;
      float qv = bf2f(qh[qi]) + bf2f(ql[qi]);
      float o  = fmaf(SQRT_V, qv, pacc[df][r]);
      u16 hv = f2bf_t(o);
      Oh_[qi] = hv;
      Ol_[qi] = f2bf_t(o - bf2f(hv));
    }
  }
}

// ---------------------------------------------------------------------------
// K4: MFMA output GEMM (round-5 structure).
// ---------------------------------------------------------------------------
__global__ __launch_bounds__(256) void k_out_mfma(
    const u16* __restrict__ Oh_, const u16* __restrict__ Ol_,
    const u16* __restrict__ Wh, const u16* __restrict__ Wl,
    const float* __restrict__ bo, float* __restrict__ out)
{
  __shared__ __align__(16) u16 Ahs[64][72];
  __shared__ __align__(16) u16 Als[64][72];
  __shared__ __align__(16) u16 Whs[64][72];
  __shared__ __align__(16) u16 Wls[64][72];
  const int t = threadIdx.x;
  const int r0 = blockIdx.x * 64;
  const int c0 = blockIdx.y * 64;
  const int bb = r0 >> 10;
  const int n0 = r0 & 1023;
  const int w = t >> 6, l = t & 63;
  const int c = l & 15, kg = l >> 4;
  const int srow = t >> 2;
  const int skoff = (t & 3) * 16;

  f32x4 acc[4];
#pragma unroll
  for (int cf = 0; cf < 4; ++cf) acc[cf] = (f32x4){0.f, 0.f, 0.f, 0.f};

  for (int kt = 0; kt < 8; ++kt) {
    __syncthreads();
    {
      const size_t ob = ((size_t)(kt * NB + bb) * NN + n0 + srow) * NDS;
      const u16* gah = &Oh_[ob + skoff];
      const u16* gal = &Ol_[ob + skoff];
      const u16* gwh = &Wh[(size_t)(c0 + srow) * ND + kt * 64 + skoff];
      const u16* gwl = &Wl[(size_t)(c0 + srow) * ND + kt * 64 + skoff];
      *(bf16x8*)&Ahs[srow][skoff]     = *(const bf16x8*)gah;
      *(bf16x8*)&Ahs[srow][skoff + 8] = *(const bf16x8*)(gah + 8);
      *(bf16x8*)&Als[srow][skoff]     = *(const bf16x8*)gal;
      *(bf16x8*)&Als[srow][skoff + 8] = *(const bf16x8*)(gal + 8);
      *(bf16x8*)&Whs[srow][skoff]     = *(const bf16x8*)gwh;
      *(bf16x8*)&Whs[srow][skoff + 8] = *(const bf16x8*)(gwh + 8);
      *(bf16x8*)&Wls[srow][skoff]     = *(const bf16x8*)gwl;
      *(bf16x8*)&Wls[srow][skoff + 8] = *(const bf16x8*)(gwl + 8);
    }
    __syncthreads();
#pragma unroll
    for (int ks = 0; ks < 2; ++ks) {
      bf16x8 Ah = *(const bf16x8*)&Ahs[w * 16 + c][ks * 32 + kg * 8];
      bf16x8 Al = *(const bf16x8*)&Als[w * 16 + c][ks * 32 + kg * 8];
#pragma unroll
      for (int cf = 0; cf < 4; ++cf) {
        bf16x8 Bh = *(const bf16x8*)&Whs[cf * 16 + c][ks * 32 + kg * 8];
        bf16x8 Bl = *(const bf16x8*)&Wls[cf * 16 + c][ks * 32 + kg * 8];
        acc[cf] = MFMA16(Ah, Bh, acc[cf]);
        acc[cf] = MFMA16(Ah, Bl, acc[cf]);
        acc[cf] = MFMA16(Al, Bh, acc[cf]);
      }
    }
  }
#pragma unroll
  for (int cf = 0; cf < 4; ++cf) {
    const int col = c0 + cf * 16 + c;
    const int d = cf * 16 + c;
    const float bv = bo[col];
#pragma unroll
    for (int r = 0; r < 4; ++r) {
      const int n = n0 + w * 16 + kg * 4 + r;
      const size_t oi = ((size_t)(blockIdx.y * NB + bb) * NN + n) * NDS + d;
      float om = bf2f(Oh_[oi]) + bf2f(Ol_[oi]);
      out[(size_t)(r0 + w * 16 + kg * 4 + r) * ND + col] =
          om + fmaxf(acc[cf][r] + bv, 0.f);
    }
  }
}

// ---------------------------------------------------------------------------
extern "C" void kernel_launch(void* const* d_in, const int* in_sizes, int n_in,
                              void* d_out, int out_size, void* d_ws, size_t ws_size,
                              hipStream_t stream) {
  const float* Q  = (const float*)d_in[0];
  const float* K  = (const float*)d_in[1];
  const float* Wq = (const float*)d_in[2];
  const float* bq = (const float*)d_in[3];
  const float* Wk = (const float*)d_in[4];
  const float* bk = (const float*)d_in[5];
  const float* Wv = (const float*)d_in[6];
  const float* bv = (const float*)d_in[7];
  const float* Wo = (const float*)d_in[8];
  const float* bo = (const float*)d_in[9];
  float* out = (float*)d_out;

  const size_t need_bytes =
      7 * SPLIT_ELEMS * sizeof(u16) + 8 * W_ELEMS * sizeof(u16) +
      4 * UV_FLOATS * sizeof(float);
  if (ws_size < need_bytes) return;

  u16* qh = (u16*)d_ws;
  u16* ql = qh + SPLIT_ELEMS;
  u16* kh = ql + SPLIT_ELEMS;
  u16* kl = kh + SPLIT_ELEMS;
  u16* vT = kl + SPLIT_ELEMS;
  u16* Oh = vT + SPLIT_ELEMS;     // phase 1-2: raw Q split; phase 3+: O hi
  u16* Ol = Oh + SPLIT_ELEMS;
  u16* wqh = Ol + SPLIT_ELEMS;
  u16* wql = wqh + W_ELEMS;
  u16* wkh = wql + W_ELEMS;
  u16* wkl = wkh + W_ELEMS;
  u16* wvh = wkl + W_ELEMS;
  u16* wvl = wvh + W_ELEMS;
  u16* woh = wvl + W_ELEMS;
  u16* wol = woh + W_ELEMS;
  float* ue = (float*)(wol + W_ELEMS);
  float* ve = ue + UV_FLOATS;
  float* qn = ve + UV_FLOATS;
  float* kn = qn + UV_FLOATS;

  u16* Qrh = Oh;                  // aliased raw input splits
  u16* Qrl = Ol;
  u16* Krh = (u16*)d_out;         // d_out fully overwritten at end
  u16* Krl = Krh + SPLIT_ELEMS;

  dim3 blk(256);
  k_split<<<dim3(4096), blk, 0, stream>>>(Q, Qrh, Qrl);
  k_split<<<dim3(4096), blk, 0, stream>>>(K, Krh, Krl);
  k_split<<<dim3(256), blk, 0, stream>>>(Wq, wqh, wql);
  k_split<<<dim3(256), blk, 0, stream>>>(Wk, wkh, wkl);
  k_split<<<dim3(256), blk, 0, stream>>>(Wv, wvh, wvl);
  k_split<<<dim3(256), blk, 0, stream>>>(Wo, woh, wol);
  k_proj_mfma<<<dim3(128, 8), blk, 0, stream>>>(Qrh, Qrl, wqh, wql, bq, qh, ql, nullptr, qn, INV_SQRT_V, 0);
  k_proj_mfma<<<dim3(128, 8), blk, 0, stream>>>(Krh, Krl, wkh, wkl, bk, kh, kl, nullptr, kn, INV_SQRT_V, 0);
  k_proj_mfma<<<dim3(128, 8), blk, 0, stream>>>(Krh, Krl, wvh, wvl, bv, nullptr, nullptr, vT, nullptr, 1.0f, 1);
  for (int it = 0; it < 3; ++it) {
    k_lse_mfma<<<dim3(512), dim3(512), 0, stream>>>(qh, ql, kh, kl, qn, kn, ve, ue, it == 0 ? 1 : 0);
    k_lse_mfma<<<dim3(512), dim3(512), 0, stream>>>(kh, kl, qh, ql, kn, qn, ue, ve, 0);
  }
  k_pv_mfma<<<dim3(512), dim3(512), 0, stream>>>(qh, ql, kh, kl, vT, qn, kn, ue, ve, Oh, Ol);
  k_out_mfma<<<dim3(128, 8), blk, 0, stream>>>(Oh, Ol, woh, wol, bo, out);
}